// Round 1
// baseline (2964.986 us; speedup 1.0000x reference)
//
#include <hip/hip_runtime.h>
#include <math.h>

// Problem constants
// B=2, T=8, H=64, W=64, C=192, WIN=(4,8,8), SHIFT=(2,4,4), HEADS=6, d=32
// N=256 tokens/window, nW=128 windows/batch, B_=256 windows total, HID=768

// ---------------------------------------------------------------- K1a: CPB MLP table
// tbl6[m][head] = relu(REL_TABLE[m] @ cpb_w1^T + cpb_b1) @ cpb_w2^T,  m in [0,1575)
__global__ __launch_bounds__(512) void cpb_table_k(const float* __restrict__ w1,
                                                   const float* __restrict__ b1,
                                                   const float* __restrict__ w2,
                                                   float* __restrict__ tbl6) {
    __shared__ float red[512];
    int m = blockIdx.x;
    int it = m / 225;
    int ih = (m / 15) % 15;
    int iw = m % 15;
    float r0 = (float)(it - 3) * (8.0f / 3.0f);
    float r1 = (float)(ih - 7) * (8.0f / 7.0f);
    float r2 = (float)(iw - 7) * (8.0f / 7.0f);
    // sign(x) * log2(|x|+1) / log2(8)
    float c0 = (r0 < 0.f ? -1.f : 1.f) * log2f(fabsf(r0) + 1.0f) * (1.0f / 3.0f);
    float c1 = (r1 < 0.f ? -1.f : 1.f) * log2f(fabsf(r1) + 1.0f) * (1.0f / 3.0f);
    float c2 = (r2 < 0.f ? -1.f : 1.f) * log2f(fabsf(r2) + 1.0f) * (1.0f / 3.0f);
    int t = threadIdx.x;
    float hv = fmaxf(0.0f, c0 * w1[3 * t] + c1 * w1[3 * t + 1] + c2 * w1[3 * t + 2] + b1[t]);
    for (int head = 0; head < 6; head++) {
        red[t] = hv * w2[head * 512 + t];
        __syncthreads();
        for (int s = 256; s > 0; s >>= 1) {
            if (t < s) red[t] += red[t + s];
            __syncthreads();
        }
        if (t == 0) tbl6[m * 6 + head] = red[0];
        __syncthreads();
    }
}

// ---------------------------------------------------------------- K1b: bias16[h][i][j] = 16*sigmoid(tbl6[rpi(i,j)][h])
__global__ __launch_bounds__(256) void bias_k(const float* __restrict__ tbl6,
                                              float* __restrict__ bias16) {
    int idx = blockIdx.x * 256 + threadIdx.x;  // h*65536 + i*256 + j
    int h = idx >> 16;
    int r = idx & 65535;
    int i = r >> 8, j = r & 255;
    int dt = (i >> 6) - (j >> 6) + 3;
    int dh = ((i >> 3) & 7) - ((j >> 3) & 7) + 7;
    int dw = (i & 7) - (j & 7) + 7;
    int rel = dt * 225 + dh * 15 + dw;
    float v = tbl6[rel * 6 + h];
    bias16[idx] = 16.0f / (1.0f + expf(-v));
}

// ---------------------------------------------------------------- K2: shifted-window gather + QKV GEMM + q/k L2-normalize
// grid 4096 (256 windows x 16 token-chunks), block 192
__global__ __launch_bounds__(192) void qkv_k(const float* __restrict__ x,
                                             const float* __restrict__ qkv_w,
                                             const float* __restrict__ qkv_b,
                                             float* __restrict__ qn,
                                             float* __restrict__ kn,
                                             float* __restrict__ vv) {
    __shared__ float xt[16 * 192];
    __shared__ float qkvt[16 * 577];  // padded row (577) to break bank conflicts in norm phase
    int tid = threadIdx.x;
    int b_ = blockIdx.x >> 4;
    int n0 = (blockIdx.x & 15) << 4;
    int b = b_ >> 7, win = b_ & 127;
    int wt = win >> 6, wh = (win >> 3) & 7, ww = win & 7;
    for (int m = 0; m < 16; m++) {
        int n = n0 + m;
        int t0 = ((wt * 4 + (n >> 6)) + 2) & 7;        // roll(-2) gather
        int h0 = ((wh * 8 + ((n >> 3) & 7)) + 4) & 63; // roll(-4)
        int w0 = ((ww * 8 + (n & 7)) + 4) & 63;        // roll(-4)
        const float* src = x + ((size_t)((b * 8 + t0) * 64 + h0) * 64 + w0) * 192;
        xt[m * 192 + tid] = src[tid];
    }
    __syncthreads();
    float acc[3][16];
#pragma unroll
    for (int rr = 0; rr < 3; rr++) {
        float bias = qkv_b[rr * 192 + tid];
#pragma unroll
        for (int m = 0; m < 16; m++) acc[rr][m] = bias;
    }
    const float4* w0p = (const float4*)(qkv_w + (size_t)(0 * 192 + tid) * 192);
    const float4* w1p = (const float4*)(qkv_w + (size_t)(1 * 192 + tid) * 192);
    const float4* w2p = (const float4*)(qkv_w + (size_t)(2 * 192 + tid) * 192);
    for (int k4 = 0; k4 < 48; k4++) {
        float4 wa = w0p[k4], wb = w1p[k4], wc = w2p[k4];
#pragma unroll
        for (int m = 0; m < 16; m++) {
            float4 xv = *(const float4*)&xt[m * 192 + k4 * 4];  // wave-uniform -> LDS broadcast
            acc[0][m] += wa.x * xv.x + wa.y * xv.y + wa.z * xv.z + wa.w * xv.w;
            acc[1][m] += wb.x * xv.x + wb.y * xv.y + wb.z * xv.z + wb.w * xv.w;
            acc[2][m] += wc.x * xv.x + wc.y * xv.y + wc.z * xv.z + wc.w * xv.w;
        }
    }
#pragma unroll
    for (int rr = 0; rr < 3; rr++)
#pragma unroll
        for (int m = 0; m < 16; m++) qkvt[m * 577 + rr * 192 + tid] = acc[rr][m];
    __syncthreads();
    {
        // 192 threads = 16 tokens x 12 rows (6 q-heads + 6 k-heads): normalize + store
        int m = tid / 12, rr = tid % 12;
        int n = n0 + m;
        int isq = (rr < 6) ? 1 : 0;
        int h = isq ? rr : rr - 6;
        const float* rowp = &qkvt[m * 577 + (isq ? 0 : 192) + h * 32];
        float ss = 0.f;
#pragma unroll
        for (int d = 0; d < 32; d++) ss += rowp[d] * rowp[d];
        float inv = 1.0f / fmaxf(sqrtf(ss), 1e-12f);
        float* dst = (isq ? qn : kn) + ((size_t)(b_ * 6 + h) * 256 + n) * 32;
#pragma unroll
        for (int d = 0; d < 32; d++) dst[d] = rowp[d] * inv;
    }
    {
        int h = tid >> 5, d = tid & 31;
        for (int m = 0; m < 16; m++)
            vv[((size_t)(b_ * 6 + h) * 256 + (n0 + m)) * 32 + d] = qkvt[m * 577 + 384 + tid];
    }
}

// ---------------------------------------------------------------- K3: cosine attention per (window, head)
// grid (6, 256), block 128; each thread owns query rows tid and tid+128.
// Single-pass softmax with analytic max bound M = scale + 16.
__global__ __launch_bounds__(128) void attn_k(const float* __restrict__ qn,
                                              const float* __restrict__ kn,
                                              const float* __restrict__ vv,
                                              const float* __restrict__ bias16,
                                              const float* __restrict__ logit_scale,
                                              float* __restrict__ att) {
    __shared__ float kl[256 * 32];  // 32KB
    __shared__ float vl[256 * 32];  // 32KB  (total exactly 64KB)
    int tid = threadIdx.x;
    int h = blockIdx.x;
    int b_ = blockIdx.y;
    const float4* kp = (const float4*)(kn + ((size_t)(b_ * 6 + h) * 256) * 32);
    const float4* vp = (const float4*)(vv + ((size_t)(b_ * 6 + h) * 256) * 32);
    float4* kl4 = (float4*)kl;
    float4* vl4 = (float4*)vl;
    for (int idx = tid; idx < 2048; idx += 128) {
        kl4[idx] = kp[idx];
        vl4[idx] = vp[idx];
    }
    float scale = __expf(fminf(logit_scale[h], 4.6051702f));  // exp(min(ls, log(100)))
    int win = b_ & 127;
    int wt4 = (win >> 6) * 4, wh8 = ((win >> 3) & 7) * 8, ww8 = (win & 7) * 8;
    auto region = [&](int n) {
        int ts = wt4 + (n >> 6), hs = wh8 + ((n >> 3) & 7), wsv = ww8 + (n & 7);
        int rt = ts < 4 ? 0 : (ts < 6 ? 1 : 2);
        int rh = hs < 56 ? 0 : (hs < 60 ? 1 : 2);
        int rw = wsv < 56 ? 0 : (wsv < 60 ? 1 : 2);
        return rt * 9 + rh * 3 + rw;
    };
    int i0 = tid, i1 = tid + 128;
    int ri0 = region(i0), ri1 = region(i1);
    float q0[32], q1[32];
    {
        const float4* q0p = (const float4*)(qn + ((size_t)(b_ * 6 + h) * 256 + i0) * 32);
        const float4* q1p = (const float4*)(qn + ((size_t)(b_ * 6 + h) * 256 + i1) * 32);
#pragma unroll
        for (int d4 = 0; d4 < 8; d4++) {
            float4 a = q0p[d4];
            q0[d4 * 4 + 0] = a.x * scale; q0[d4 * 4 + 1] = a.y * scale;
            q0[d4 * 4 + 2] = a.z * scale; q0[d4 * 4 + 3] = a.w * scale;
            float4 bq = q1p[d4];
            q1[d4 * 4 + 0] = bq.x * scale; q1[d4 * 4 + 1] = bq.y * scale;
            q1[d4 * 4 + 2] = bq.z * scale; q1[d4 * 4 + 3] = bq.w * scale;
        }
    }
    __syncthreads();
    const float* bias0 = bias16 + ((size_t)h << 16) + (size_t)i0 * 256;
    const float* bias1 = bias16 + ((size_t)h << 16) + (size_t)i1 * 256;
    float M = scale + 16.0f;
    float l0 = 0.f, l1 = 0.f;
    float a0[32], a1[32];
#pragma unroll
    for (int d = 0; d < 32; d++) { a0[d] = 0.f; a1[d] = 0.f; }
    for (int j = 0; j < 256; j++) {
        float d0 = 0.f, d1 = 0.f;
#pragma unroll
        for (int d4 = 0; d4 < 8; d4++) {
            float4 kv = kl4[j * 8 + d4];  // wave-uniform j -> broadcast
            d0 += q0[d4 * 4] * kv.x + q0[d4 * 4 + 1] * kv.y + q0[d4 * 4 + 2] * kv.z + q0[d4 * 4 + 3] * kv.w;
            d1 += q1[d4 * 4] * kv.x + q1[d4 * 4 + 1] * kv.y + q1[d4 * 4 + 2] * kv.z + q1[d4 * 4 + 3] * kv.w;
        }
        int rgj = region(j);  // uniform -> SALU
        float s0 = d0 + bias0[j] + (rgj == ri0 ? 0.0f : -100.0f);
        float s1 = d1 + bias1[j] + (rgj == ri1 ? 0.0f : -100.0f);
        float p0 = __expf(s0 - M);
        float p1 = __expf(s1 - M);
        l0 += p0; l1 += p1;
#pragma unroll
        for (int d4 = 0; d4 < 8; d4++) {
            float4 vq = vl4[j * 8 + d4];
            a0[d4 * 4 + 0] += p0 * vq.x; a0[d4 * 4 + 1] += p0 * vq.y;
            a0[d4 * 4 + 2] += p0 * vq.z; a0[d4 * 4 + 3] += p0 * vq.w;
            a1[d4 * 4 + 0] += p1 * vq.x; a1[d4 * 4 + 1] += p1 * vq.y;
            a1[d4 * 4 + 2] += p1 * vq.z; a1[d4 * 4 + 3] += p1 * vq.w;
        }
    }
    float inv0 = 1.0f / l0, inv1 = 1.0f / l1;
    float4* o0 = (float4*)(att + ((size_t)b_ * 256 + i0) * 192 + h * 32);
    float4* o1 = (float4*)(att + ((size_t)b_ * 256 + i1) * 192 + h * 32);
#pragma unroll
    for (int d4 = 0; d4 < 8; d4++) {
        o0[d4] = make_float4(a0[d4 * 4] * inv0, a0[d4 * 4 + 1] * inv0, a0[d4 * 4 + 2] * inv0, a0[d4 * 4 + 3] * inv0);
        o1[d4] = make_float4(a1[d4 * 4] * inv1, a1[d4 * 4 + 1] * inv1, a1[d4 * 4 + 2] * inv1, a1[d4 * 4 + 3] * inv1);
    }
}

// ---------------------------------------------------------------- K4: out-proj + window_reverse + roll + res-post-LN + residual
// grid 4096 (256 windows x 16 chunks), block 192. Writes x_mid into d_out.
__global__ __launch_bounds__(192) void proj_k(const float* __restrict__ att,
                                              const float* __restrict__ proj_w,
                                              const float* __restrict__ proj_b,
                                              const float* __restrict__ x,
                                              const float* __restrict__ g1,
                                              const float* __restrict__ b1n,
                                              float* __restrict__ out) {
    __shared__ float xa[16 * 192];
    __shared__ float ot[16 * 193];  // +1 pad for token-major stat reads
    __shared__ float stats[32];
    int tid = threadIdx.x;
    int b_ = blockIdx.x >> 4;
    int n0 = (blockIdx.x & 15) << 4;
    for (int m = 0; m < 16; m++)
        xa[m * 192 + tid] = att[((size_t)b_ * 256 + n0 + m) * 192 + tid];
    __syncthreads();
    float acc[16];
    float pb = proj_b[tid];
#pragma unroll
    for (int m = 0; m < 16; m++) acc[m] = pb;
    const float4* wrow = (const float4*)(proj_w + (size_t)tid * 192);
    for (int k4 = 0; k4 < 48; k4++) {
        float4 w4 = wrow[k4];
#pragma unroll
        for (int m = 0; m < 16; m++) {
            float4 xv = *(const float4*)&xa[m * 192 + k4 * 4];
            acc[m] += w4.x * xv.x + w4.y * xv.y + w4.z * xv.z + w4.w * xv.w;
        }
    }
#pragma unroll
    for (int m = 0; m < 16; m++) ot[m * 193 + tid] = acc[m];
    __syncthreads();
    if (tid < 16) {
        float s = 0.f, ss = 0.f;
        for (int c = 0; c < 192; c++) { float v = ot[tid * 193 + c]; s += v; ss += v * v; }
        float mean = s * (1.0f / 192.0f);
        float var = ss * (1.0f / 192.0f) - mean * mean;
        stats[tid] = mean;
        stats[16 + tid] = 1.0f / sqrtf(var + 1e-5f);
    }
    __syncthreads();
    int b = b_ >> 7, win = b_ & 127;
    int wt = win >> 6, wh = (win >> 3) & 7, ww = win & 7;
    float gv = g1[tid], bv = b1n[tid];
    for (int m = 0; m < 16; m++) {
        int n = n0 + m;
        int t0 = ((wt * 4 + (n >> 6)) + 2) & 7;        // roll(+2) scatter == same index math as gather
        int h0 = ((wh * 8 + ((n >> 3) & 7)) + 4) & 63;
        int w0 = ((ww * 8 + (n & 7)) + 4) & 63;
        size_t gb = ((size_t)((b * 8 + t0) * 64 + h0) * 64 + w0) * 192;
        float v = (ot[m * 193 + tid] - stats[m]) * stats[16 + m] * gv + bv;
        out[gb + tid] = x[gb + tid] + v;  // shortcut + LN(attn-branch)
    }
}

// ---------------------------------------------------------------- K5: MLP (fc1 + exact GELU + fc2 + LN + residual), in-place on d_out
// grid 8192 (65536 tokens / 8), block 192
__global__ __launch_bounds__(192) void mlp_k(const float* __restrict__ fc1_w,
                                             const float* __restrict__ fc1_b,
                                             const float* __restrict__ fc2_w,
                                             const float* __restrict__ fc2_b,
                                             const float* __restrict__ g2,
                                             const float* __restrict__ b2,
                                             float* __restrict__ out) {
    __shared__ float xm[8 * 192];
    __shared__ float h1[8 * 768];
    __shared__ float zt[8 * 193];
    __shared__ float stats[16];
    int tid = threadIdx.x;
    size_t tk0 = (size_t)blockIdx.x * 8;
    for (int m = 0; m < 8; m++)
        xm[m * 192 + tid] = out[(tk0 + m) * 192 + tid];
    __syncthreads();
    float acc[4][8];
#pragma unroll
    for (int rr = 0; rr < 4; rr++) {
        float bias = fc1_b[rr * 192 + tid];
#pragma unroll
        for (int m = 0; m < 8; m++) acc[rr][m] = bias;
    }
    const float4* wr0 = (const float4*)(fc1_w + (size_t)(0 * 192 + tid) * 192);
    const float4* wr1 = (const float4*)(fc1_w + (size_t)(1 * 192 + tid) * 192);
    const float4* wr2 = (const float4*)(fc1_w + (size_t)(2 * 192 + tid) * 192);
    const float4* wr3 = (const float4*)(fc1_w + (size_t)(3 * 192 + tid) * 192);
    for (int k4 = 0; k4 < 48; k4++) {
        float4 wa = wr0[k4], wb = wr1[k4], wc = wr2[k4], wd = wr3[k4];
#pragma unroll
        for (int m = 0; m < 8; m++) {
            float4 xv = *(const float4*)&xm[m * 192 + k4 * 4];
            acc[0][m] += wa.x * xv.x + wa.y * xv.y + wa.z * xv.z + wa.w * xv.w;
            acc[1][m] += wb.x * xv.x + wb.y * xv.y + wb.z * xv.z + wb.w * xv.w;
            acc[2][m] += wc.x * xv.x + wc.y * xv.y + wc.z * xv.z + wc.w * xv.w;
            acc[3][m] += wd.x * xv.x + wd.y * xv.y + wd.z * xv.z + wd.w * xv.w;
        }
    }
#pragma unroll
    for (int rr = 0; rr < 4; rr++)
#pragma unroll
        for (int m = 0; m < 8; m++) {
            float u = acc[rr][m];
            h1[m * 768 + rr * 192 + tid] = 0.5f * u * (1.0f + erff(u * 0.70710678118654752f));
        }
    __syncthreads();
    float a2[8];
    float fb = fc2_b[tid];
#pragma unroll
    for (int m = 0; m < 8; m++) a2[m] = fb;
    const float4* w2r = (const float4*)(fc2_w + (size_t)tid * 768);
    for (int k4 = 0; k4 < 192; k4++) {
        float4 w4 = w2r[k4];
#pragma unroll
        for (int m = 0; m < 8; m++) {
            float4 hv = *(const float4*)&h1[m * 768 + k4 * 4];
            a2[m] += w4.x * hv.x + w4.y * hv.y + w4.z * hv.z + w4.w * hv.w;
        }
    }
#pragma unroll
    for (int m = 0; m < 8; m++) zt[m * 193 + tid] = a2[m];
    __syncthreads();
    if (tid < 8) {
        float s = 0.f, ss = 0.f;
        for (int c = 0; c < 192; c++) { float v = zt[tid * 193 + c]; s += v; ss += v * v; }
        float mean = s * (1.0f / 192.0f);
        float var = ss * (1.0f / 192.0f) - mean * mean;
        stats[tid] = mean;
        stats[8 + tid] = 1.0f / sqrtf(var + 1e-5f);
    }
    __syncthreads();
    float gv = g2[tid], bv = b2[tid];
#pragma unroll
    for (int m = 0; m < 8; m++) {
        float v = (zt[m * 193 + tid] - stats[m]) * stats[8 + m] * gv + bv;
        out[(tk0 + m) * 192 + tid] = xm[m * 192 + tid] + v;
    }
}

// ---------------------------------------------------------------- launch
extern "C" void kernel_launch(void* const* d_in, const int* in_sizes, int n_in,
                              void* d_out, int out_size, void* d_ws, size_t ws_size,
                              hipStream_t stream) {
    const float* x           = (const float*)d_in[0];
    const float* qkv_w       = (const float*)d_in[1];
    const float* qkv_b       = (const float*)d_in[2];
    const float* proj_w      = (const float*)d_in[3];
    const float* proj_b      = (const float*)d_in[4];
    const float* cpb_w1      = (const float*)d_in[5];
    const float* cpb_b1      = (const float*)d_in[6];
    const float* cpb_w2      = (const float*)d_in[7];
    const float* logit_scale = (const float*)d_in[8];
    const float* norm1_g     = (const float*)d_in[9];
    const float* norm1_b     = (const float*)d_in[10];
    const float* norm2_g     = (const float*)d_in[11];
    const float* norm2_b     = (const float*)d_in[12];
    const float* fc1_w       = (const float*)d_in[13];
    const float* fc1_b       = (const float*)d_in[14];
    const float* fc2_w       = (const float*)d_in[15];
    const float* fc2_b       = (const float*)d_in[16];
    float* out = (float*)d_out;

    float* ws = (float*)d_ws;
    const size_t QKVE = (size_t)256 * 6 * 256 * 32;  // 12,582,912 per tensor
    float* qn     = ws;
    float* kn     = qn + QKVE;
    float* vv     = kn + QKVE;
    float* att    = vv + QKVE;
    float* bias16 = att + (size_t)256 * 256 * 192;  // 12,582,912
    float* tbl6   = bias16 + (size_t)6 * 256 * 256; // 393,216

    hipLaunchKernelGGL(cpb_table_k, dim3(1575), dim3(512), 0, stream, cpb_w1, cpb_b1, cpb_w2, tbl6);
    hipLaunchKernelGGL(bias_k, dim3(1536), dim3(256), 0, stream, tbl6, bias16);
    hipLaunchKernelGGL(qkv_k, dim3(4096), dim3(192), 0, stream, x, qkv_w, qkv_b, qn, kn, vv);
    hipLaunchKernelGGL(attn_k, dim3(6, 256), dim3(128), 0, stream, qn, kn, vv, bias16, logit_scale, att);
    hipLaunchKernelGGL(proj_k, dim3(4096), dim3(192), 0, stream, att, proj_w, proj_b, x, norm1_g, norm1_b, out);
    hipLaunchKernelGGL(mlp_k, dim3(8192), dim3(192), 0, stream, fc1_w, fc1_b, fc2_w, fc2_b, norm2_g, norm2_b, out);
}

// Round 2
// 1350.772 us; speedup vs baseline: 2.1950x; 2.1950x over previous
//
#include <hip/hip_runtime.h>
#include <math.h>

// Problem constants
// B=2, T=8, H=64, W=64, C=192, WIN=(4,8,8), SHIFT=(2,4,4), HEADS=6, d=32
// N=256 tokens/window, nW=128 windows/batch, B_=256 windows total, HID=768

typedef short short8 __attribute__((ext_vector_type(8)));
typedef float f32x4 __attribute__((ext_vector_type(4)));

__device__ __forceinline__ short f2bf(float f) {
    union { float f; unsigned u; } v; v.f = f;
    unsigned r = v.u + 0x7FFF + ((v.u >> 16) & 1);  // RNE
    return (short)(r >> 16);
}

// ---------------------------------------------------------------- K0: pack fp32 weight (Nout, K) -> bf16 B-fragment order
// frag (nt, kt): lane l holds B[k=(l>>4)*8+j][n=l&15] = W[nt*16+(l&15)][kt*32+(l>>4)*8+j]
// dst frag index = (nt*(K/32)+kt)*64 + l, 8 bf16 each (16B, coalesced)
__global__ __launch_bounds__(64) void pack_w_k(const float* __restrict__ w,
                                               short* __restrict__ dst, int K) {
    int lane = threadIdx.x;
    int ktn = K >> 5;
    int nt = blockIdx.x / ktn, kt = blockIdx.x % ktn;
    int r = lane & 15, q = lane >> 4;
    const float* src = w + (size_t)(nt * 16 + r) * K + kt * 32 + q * 8;
    short8 v;
#pragma unroll
    for (int j = 0; j < 8; j++) v[j] = f2bf(src[j]);
    ((short8*)dst)[(size_t)blockIdx.x * 64 + lane] = v;
}

// ---------------------------------------------------------------- K1a: CPB MLP table
__global__ __launch_bounds__(512) void cpb_table_k(const float* __restrict__ w1,
                                                   const float* __restrict__ b1,
                                                   const float* __restrict__ w2,
                                                   float* __restrict__ tbl6) {
    __shared__ float red[512];
    int m = blockIdx.x;
    int it = m / 225;
    int ih = (m / 15) % 15;
    int iw = m % 15;
    float r0 = (float)(it - 3) * (8.0f / 3.0f);
    float r1 = (float)(ih - 7) * (8.0f / 7.0f);
    float r2 = (float)(iw - 7) * (8.0f / 7.0f);
    float c0 = (r0 < 0.f ? -1.f : 1.f) * log2f(fabsf(r0) + 1.0f) * (1.0f / 3.0f);
    float c1 = (r1 < 0.f ? -1.f : 1.f) * log2f(fabsf(r1) + 1.0f) * (1.0f / 3.0f);
    float c2 = (r2 < 0.f ? -1.f : 1.f) * log2f(fabsf(r2) + 1.0f) * (1.0f / 3.0f);
    int t = threadIdx.x;
    float hv = fmaxf(0.0f, c0 * w1[3 * t] + c1 * w1[3 * t + 1] + c2 * w1[3 * t + 2] + b1[t]);
    for (int head = 0; head < 6; head++) {
        red[t] = hv * w2[head * 512 + t];
        __syncthreads();
        for (int s = 256; s > 0; s >>= 1) {
            if (t < s) red[t] += red[t + s];
            __syncthreads();
        }
        if (t == 0) tbl6[m * 6 + head] = red[0];
        __syncthreads();
    }
}

// ---------------------------------------------------------------- K1b: bias16[h][i][j] = 16*sigmoid(tbl6[rpi(i,j)][h])
__global__ __launch_bounds__(256) void bias_k(const float* __restrict__ tbl6,
                                              float* __restrict__ bias16) {
    int idx = blockIdx.x * 256 + threadIdx.x;
    int h = idx >> 16;
    int r = idx & 65535;
    int i = r >> 8, j = r & 255;
    int dt = (i >> 6) - (j >> 6) + 3;
    int dh = ((i >> 3) & 7) - ((j >> 3) & 7) + 7;
    int dw = (i & 7) - (j & 7) + 7;
    int rel = dt * 225 + dh * 15 + dw;
    float v = tbl6[rel * 6 + h];
    bias16[idx] = 16.0f / (1.0f + expf(-v));
}

// ---------------------------------------------------------------- K2: shifted-window gather + QKV GEMM + q/k L2-normalize
__global__ __launch_bounds__(192) void qkv_k(const float* __restrict__ x,
                                             const float* __restrict__ qkv_w,
                                             const float* __restrict__ qkv_b,
                                             float* __restrict__ qn,
                                             float* __restrict__ kn,
                                             float* __restrict__ vv) {
    __shared__ float xt[16 * 192];
    __shared__ float qkvt[16 * 577];
    int tid = threadIdx.x;
    int b_ = blockIdx.x >> 4;
    int n0 = (blockIdx.x & 15) << 4;
    int b = b_ >> 7, win = b_ & 127;
    int wt = win >> 6, wh = (win >> 3) & 7, ww = win & 7;
    for (int m = 0; m < 16; m++) {
        int n = n0 + m;
        int t0 = ((wt * 4 + (n >> 6)) + 2) & 7;
        int h0 = ((wh * 8 + ((n >> 3) & 7)) + 4) & 63;
        int w0 = ((ww * 8 + (n & 7)) + 4) & 63;
        const float* src = x + ((size_t)((b * 8 + t0) * 64 + h0) * 64 + w0) * 192;
        xt[m * 192 + tid] = src[tid];
    }
    __syncthreads();
    float acc[3][16];
#pragma unroll
    for (int rr = 0; rr < 3; rr++) {
        float bias = qkv_b[rr * 192 + tid];
#pragma unroll
        for (int m = 0; m < 16; m++) acc[rr][m] = bias;
    }
    const float4* w0p = (const float4*)(qkv_w + (size_t)(0 * 192 + tid) * 192);
    const float4* w1p = (const float4*)(qkv_w + (size_t)(1 * 192 + tid) * 192);
    const float4* w2p = (const float4*)(qkv_w + (size_t)(2 * 192 + tid) * 192);
    for (int k4 = 0; k4 < 48; k4++) {
        float4 wa = w0p[k4], wb = w1p[k4], wc = w2p[k4];
#pragma unroll
        for (int m = 0; m < 16; m++) {
            float4 xv = *(const float4*)&xt[m * 192 + k4 * 4];
            acc[0][m] += wa.x * xv.x + wa.y * xv.y + wa.z * xv.z + wa.w * xv.w;
            acc[1][m] += wb.x * xv.x + wb.y * xv.y + wb.z * xv.z + wb.w * xv.w;
            acc[2][m] += wc.x * xv.x + wc.y * xv.y + wc.z * xv.z + wc.w * xv.w;
        }
    }
#pragma unroll
    for (int rr = 0; rr < 3; rr++)
#pragma unroll
        for (int m = 0; m < 16; m++) qkvt[m * 577 + rr * 192 + tid] = acc[rr][m];
    __syncthreads();
    {
        int m = tid / 12, rr = tid % 12;
        int n = n0 + m;
        int isq = (rr < 6) ? 1 : 0;
        int h = isq ? rr : rr - 6;
        const float* rowp = &qkvt[m * 577 + (isq ? 0 : 192) + h * 32];
        float ss = 0.f;
#pragma unroll
        for (int d = 0; d < 32; d++) ss += rowp[d] * rowp[d];
        float inv = 1.0f / fmaxf(sqrtf(ss), 1e-12f);
        float* dst = (isq ? qn : kn) + ((size_t)(b_ * 6 + h) * 256 + n) * 32;
#pragma unroll
        for (int d = 0; d < 32; d++) dst[d] = rowp[d] * inv;
    }
    {
        int h = tid >> 5, d = tid & 31;
        for (int m = 0; m < 16; m++)
            vv[((size_t)(b_ * 6 + h) * 256 + (n0 + m)) * 32 + d] = qkvt[m * 577 + 384 + tid];
    }
}

// ---------------------------------------------------------------- K3: cosine attention per (window, head)
__global__ __launch_bounds__(128) void attn_k(const float* __restrict__ qn,
                                              const float* __restrict__ kn,
                                              const float* __restrict__ vv,
                                              const float* __restrict__ bias16,
                                              const float* __restrict__ logit_scale,
                                              float* __restrict__ att) {
    __shared__ float kl[256 * 32];
    __shared__ float vl[256 * 32];
    int tid = threadIdx.x;
    int h = blockIdx.x;
    int b_ = blockIdx.y;
    const float4* kp = (const float4*)(kn + ((size_t)(b_ * 6 + h) * 256) * 32);
    const float4* vp = (const float4*)(vv + ((size_t)(b_ * 6 + h) * 256) * 32);
    float4* kl4 = (float4*)kl;
    float4* vl4 = (float4*)vl;
    for (int idx = tid; idx < 2048; idx += 128) {
        kl4[idx] = kp[idx];
        vl4[idx] = vp[idx];
    }
    float scale = __expf(fminf(logit_scale[h], 4.6051702f));
    int win = b_ & 127;
    int wt4 = (win >> 6) * 4, wh8 = ((win >> 3) & 7) * 8, ww8 = (win & 7) * 8;
    auto region = [&](int n) {
        int ts = wt4 + (n >> 6), hs = wh8 + ((n >> 3) & 7), wsv = ww8 + (n & 7);
        int rt = ts < 4 ? 0 : (ts < 6 ? 1 : 2);
        int rh = hs < 56 ? 0 : (hs < 60 ? 1 : 2);
        int rw = wsv < 56 ? 0 : (wsv < 60 ? 1 : 2);
        return rt * 9 + rh * 3 + rw;
    };
    int i0 = tid, i1 = tid + 128;
    int ri0 = region(i0), ri1 = region(i1);
    float q0[32], q1[32];
    {
        const float4* q0p = (const float4*)(qn + ((size_t)(b_ * 6 + h) * 256 + i0) * 32);
        const float4* q1p = (const float4*)(qn + ((size_t)(b_ * 6 + h) * 256 + i1) * 32);
#pragma unroll
        for (int d4 = 0; d4 < 8; d4++) {
            float4 a = q0p[d4];
            q0[d4 * 4 + 0] = a.x * scale; q0[d4 * 4 + 1] = a.y * scale;
            q0[d4 * 4 + 2] = a.z * scale; q0[d4 * 4 + 3] = a.w * scale;
            float4 bq = q1p[d4];
            q1[d4 * 4 + 0] = bq.x * scale; q1[d4 * 4 + 1] = bq.y * scale;
            q1[d4 * 4 + 2] = bq.z * scale; q1[d4 * 4 + 3] = bq.w * scale;
        }
    }
    __syncthreads();
    const float* bias0 = bias16 + ((size_t)h << 16) + (size_t)i0 * 256;
    const float* bias1 = bias16 + ((size_t)h << 16) + (size_t)i1 * 256;
    float M = scale + 16.0f;
    float l0 = 0.f, l1 = 0.f;
    float a0[32], a1[32];
#pragma unroll
    for (int d = 0; d < 32; d++) { a0[d] = 0.f; a1[d] = 0.f; }
    for (int j = 0; j < 256; j++) {
        float d0 = 0.f, d1 = 0.f;
#pragma unroll
        for (int d4 = 0; d4 < 8; d4++) {
            float4 kv = kl4[j * 8 + d4];
            d0 += q0[d4 * 4] * kv.x + q0[d4 * 4 + 1] * kv.y + q0[d4 * 4 + 2] * kv.z + q0[d4 * 4 + 3] * kv.w;
            d1 += q1[d4 * 4] * kv.x + q1[d4 * 4 + 1] * kv.y + q1[d4 * 4 + 2] * kv.z + q1[d4 * 4 + 3] * kv.w;
        }
        int rgj = region(j);
        float s0 = d0 + bias0[j] + (rgj == ri0 ? 0.0f : -100.0f);
        float s1 = d1 + bias1[j] + (rgj == ri1 ? 0.0f : -100.0f);
        float p0 = __expf(s0 - M);
        float p1 = __expf(s1 - M);
        l0 += p0; l1 += p1;
#pragma unroll
        for (int d4 = 0; d4 < 8; d4++) {
            float4 vq = vl4[j * 8 + d4];
            a0[d4 * 4 + 0] += p0 * vq.x; a0[d4 * 4 + 1] += p0 * vq.y;
            a0[d4 * 4 + 2] += p0 * vq.z; a0[d4 * 4 + 3] += p0 * vq.w;
            a1[d4 * 4 + 0] += p1 * vq.x; a1[d4 * 4 + 1] += p1 * vq.y;
            a1[d4 * 4 + 2] += p1 * vq.z; a1[d4 * 4 + 3] += p1 * vq.w;
        }
    }
    float inv0 = 1.0f / l0, inv1 = 1.0f / l1;
    float4* o0 = (float4*)(att + ((size_t)b_ * 256 + i0) * 192 + h * 32);
    float4* o1 = (float4*)(att + ((size_t)b_ * 256 + i1) * 192 + h * 32);
#pragma unroll
    for (int d4 = 0; d4 < 8; d4++) {
        o0[d4] = make_float4(a0[d4 * 4] * inv0, a0[d4 * 4 + 1] * inv0, a0[d4 * 4 + 2] * inv0, a0[d4 * 4 + 3] * inv0);
        o1[d4] = make_float4(a1[d4 * 4] * inv1, a1[d4 * 4 + 1] * inv1, a1[d4 * 4 + 2] * inv1, a1[d4 * 4 + 3] * inv1);
    }
}

// ---------------------------------------------------------------- K4: out-proj + window_reverse + roll + res-post-LN + residual
__global__ __launch_bounds__(192) void proj_k(const float* __restrict__ att,
                                              const float* __restrict__ proj_w,
                                              const float* __restrict__ proj_b,
                                              const float* __restrict__ x,
                                              const float* __restrict__ g1,
                                              const float* __restrict__ b1n,
                                              float* __restrict__ out) {
    __shared__ float xa[16 * 192];
    __shared__ float ot[16 * 193];
    __shared__ float stats[32];
    int tid = threadIdx.x;
    int b_ = blockIdx.x >> 4;
    int n0 = (blockIdx.x & 15) << 4;
    for (int m = 0; m < 16; m++)
        xa[m * 192 + tid] = att[((size_t)b_ * 256 + n0 + m) * 192 + tid];
    __syncthreads();
    float acc[16];
    float pb = proj_b[tid];
#pragma unroll
    for (int m = 0; m < 16; m++) acc[m] = pb;
    const float4* wrow = (const float4*)(proj_w + (size_t)tid * 192);
    for (int k4 = 0; k4 < 48; k4++) {
        float4 w4 = wrow[k4];
#pragma unroll
        for (int m = 0; m < 16; m++) {
            float4 xv = *(const float4*)&xa[m * 192 + k4 * 4];
            acc[m] += w4.x * xv.x + w4.y * xv.y + w4.z * xv.z + w4.w * xv.w;
        }
    }
#pragma unroll
    for (int m = 0; m < 16; m++) ot[m * 193 + tid] = acc[m];
    __syncthreads();
    if (tid < 16) {
        float s = 0.f, ss = 0.f;
        for (int c = 0; c < 192; c++) { float v = ot[tid * 193 + c]; s += v; ss += v * v; }
        float mean = s * (1.0f / 192.0f);
        float var = ss * (1.0f / 192.0f) - mean * mean;
        stats[tid] = mean;
        stats[16 + tid] = 1.0f / sqrtf(var + 1e-5f);
    }
    __syncthreads();
    int b = b_ >> 7, win = b_ & 127;
    int wt = win >> 6, wh = (win >> 3) & 7, ww = win & 7;
    float gv = g1[tid], bv = b1n[tid];
    for (int m = 0; m < 16; m++) {
        int n = n0 + m;
        int t0 = ((wt * 4 + (n >> 6)) + 2) & 7;
        int h0 = ((wh * 8 + ((n >> 3) & 7)) + 4) & 63;
        int w0 = ((ww * 8 + (n & 7)) + 4) & 63;
        size_t gb = ((size_t)((b * 8 + t0) * 64 + h0) * 64 + w0) * 192;
        float v = (ot[m * 193 + tid] - stats[m]) * stats[16 + m] * gv + bv;
        out[gb + tid] = x[gb + tid] + v;
    }
}

// ---------------------------------------------------------------- K5: MLP via bf16 MFMA, fused fc1+GELU+fc2+LN+residual
// block=256 (4 waves), 32 tokens/block, grid 2048. x_mid fp32 lives in `out`.
// Phase 1: H[32][768] = gelu(X W1^T + b1)  -> LDS bf16 (row stride 776)
// Phase 2: Z[32][192] = H W2^T + b2        -> LDS fp32 (reuse H region)
// Epilogue: out = x_mid + LN(Z)
#define HSTR 776
__global__ __launch_bounds__(256) void mlp_mfma_k(const short* __restrict__ w1p,
                                                  const short* __restrict__ w2p,
                                                  const float* __restrict__ fc1_b,
                                                  const float* __restrict__ fc2_b,
                                                  const float* __restrict__ g2,
                                                  const float* __restrict__ b2,
                                                  float* __restrict__ out) {
    __shared__ short Hs[32 * HSTR];      // 49664 B; reused as Z fp32 [32][193]
    __shared__ float ps[32][8];
    __shared__ float pss[32][8];
    __shared__ float mean_s[32], inv_s[32];
    int tid = threadIdx.x;
    int lane = tid & 63, w = tid >> 6;
    int r = lane & 15, q = lane >> 4;
    size_t tok0 = (size_t)blockIdx.x * 32;

    // A fragments from fp32 x_mid: af[m][kt], lane holds A[m=r][k=q*8+j]
    short8 af[2][6];
#pragma unroll
    for (int m = 0; m < 2; m++)
#pragma unroll
        for (int kt = 0; kt < 6; kt++) {
            const float* src = out + (tok0 + m * 16 + r) * 192 + kt * 32 + q * 8;
            float4 x0 = *(const float4*)src;
            float4 x1 = *(const float4*)(src + 4);
            short8 v;
            v[0] = f2bf(x0.x); v[1] = f2bf(x0.y); v[2] = f2bf(x0.z); v[3] = f2bf(x0.w);
            v[4] = f2bf(x1.x); v[5] = f2bf(x1.y); v[6] = f2bf(x1.z); v[7] = f2bf(x1.w);
            af[m][kt] = v;
        }

    // ---- phase 1: wave w computes H cols [w*192, (w+1)*192)
    for (int ntl = 0; ntl < 12; ntl++) {
        int nt = w * 12 + ntl;           // global n-tile 0..47
        float bias = fc1_b[nt * 16 + r];
        short8 bfr[6];
#pragma unroll
        for (int kt = 0; kt < 6; kt++)
            bfr[kt] = ((const short8*)w1p)[(size_t)(nt * 6 + kt) * 64 + lane];
        f32x4 acc0 = {bias, bias, bias, bias};
        f32x4 acc1 = {bias, bias, bias, bias};
#pragma unroll
        for (int kt = 0; kt < 6; kt++) {
            acc0 = __builtin_amdgcn_mfma_f32_16x16x32_bf16(af[0][kt], bfr[kt], acc0, 0, 0, 0);
            acc1 = __builtin_amdgcn_mfma_f32_16x16x32_bf16(af[1][kt], bfr[kt], acc1, 0, 0, 0);
        }
        int col = nt * 16 + r;
#pragma unroll
        for (int reg = 0; reg < 4; reg++) {
            float u0 = acc0[reg];
            float u1 = acc1[reg];
            float gl0 = 0.5f * u0 * (1.0f + erff(u0 * 0.70710678118654752f));
            float gl1 = 0.5f * u1 * (1.0f + erff(u1 * 0.70710678118654752f));
            Hs[(q * 4 + reg) * HSTR + col] = f2bf(gl0);
            Hs[(16 + q * 4 + reg) * HSTR + col] = f2bf(gl1);
        }
    }
    __syncthreads();

    // ---- phase 2: wave w computes Z n-tiles {3w, 3w+1, 3w+2}
    f32x4 acc2[2][3];
#pragma unroll
    for (int m = 0; m < 2; m++)
#pragma unroll
        for (int n = 0; n < 3; n++) acc2[m][n] = (f32x4){0.f, 0.f, 0.f, 0.f};
    for (int kk = 0; kk < 24; kk++) {
        short8 a0 = *(const short8*)&Hs[(r) * HSTR + kk * 32 + q * 8];
        short8 a1 = *(const short8*)&Hs[(16 + r) * HSTR + kk * 32 + q * 8];
#pragma unroll
        for (int n = 0; n < 3; n++) {
            int nt = w * 3 + n;
            short8 bfr = ((const short8*)w2p)[(size_t)(nt * 24 + kk) * 64 + lane];
            acc2[0][n] = __builtin_amdgcn_mfma_f32_16x16x32_bf16(a0, bfr, acc2[0][n], 0, 0, 0);
            acc2[1][n] = __builtin_amdgcn_mfma_f32_16x16x32_bf16(a1, bfr, acc2[1][n], 0, 0, 0);
        }
    }
    __syncthreads();  // all H reads complete before overwriting region with Z
    float* Z = (float*)Hs;  // [32][193]
#pragma unroll
    for (int m = 0; m < 2; m++)
#pragma unroll
        for (int n = 0; n < 3; n++) {
            int nt = w * 3 + n;
            int col = nt * 16 + r;
            float bias2 = fc2_b[col];
#pragma unroll
            for (int reg = 0; reg < 4; reg++)
                Z[(m * 16 + q * 4 + reg) * 193 + col] = acc2[m][n][reg] + bias2;
        }
    __syncthreads();

    // ---- LN stats: 8 threads per token
    {
        int token = tid >> 3, part = tid & 7;
        float s = 0.f, ss = 0.f;
        const float* zr = &Z[token * 193 + part * 24];
#pragma unroll
        for (int c = 0; c < 24; c++) { float v = zr[c]; s += v; ss += v * v; }
        ps[token][part] = s; pss[token][part] = ss;
    }
    __syncthreads();
    if (tid < 32) {
        float s = 0.f, ss = 0.f;
#pragma unroll
        for (int p = 0; p < 8; p++) { s += ps[tid][p]; ss += pss[tid][p]; }
        float mean = s * (1.0f / 192.0f);
        float var = ss * (1.0f / 192.0f) - mean * mean;
        mean_s[tid] = mean;
        inv_s[tid] = 1.0f / sqrtf(var + 1e-5f);
    }
    __syncthreads();
    // ---- epilogue: out = x_mid + LN(Z)*g2 + b2   (6144 elems, 24/thread)
    for (int rep = 0; rep < 24; rep++) {
        int idx = rep * 256 + tid;
        int token = idx / 192;
        int ch = idx - token * 192;
        float v = (Z[token * 193 + ch] - mean_s[token]) * inv_s[token] * g2[ch] + b2[ch];
        size_t gi = (tok0 + token) * 192 + ch;
        out[gi] = out[gi] + v;
    }
}

// ---------------------------------------------------------------- launch
extern "C" void kernel_launch(void* const* d_in, const int* in_sizes, int n_in,
                              void* d_out, int out_size, void* d_ws, size_t ws_size,
                              hipStream_t stream) {
    const float* x           = (const float*)d_in[0];
    const float* qkv_w       = (const float*)d_in[1];
    const float* qkv_b       = (const float*)d_in[2];
    const float* proj_w      = (const float*)d_in[3];
    const float* proj_b      = (const float*)d_in[4];
    const float* cpb_w1      = (const float*)d_in[5];
    const float* cpb_b1      = (const float*)d_in[6];
    const float* cpb_w2      = (const float*)d_in[7];
    const float* logit_scale = (const float*)d_in[8];
    const float* norm1_g     = (const float*)d_in[9];
    const float* norm1_b     = (const float*)d_in[10];
    const float* norm2_g     = (const float*)d_in[11];
    const float* norm2_b     = (const float*)d_in[12];
    const float* fc1_w       = (const float*)d_in[13];
    const float* fc1_b       = (const float*)d_in[14];
    const float* fc2_w       = (const float*)d_in[15];
    const float* fc2_b       = (const float*)d_in[16];
    float* out = (float*)d_out;

    float* ws = (float*)d_ws;
    const size_t QKVE = (size_t)256 * 6 * 256 * 32;  // 12,582,912 per tensor
    float* qn     = ws;
    float* kn     = qn + QKVE;
    float* vv     = kn + QKVE;
    float* att    = vv + QKVE;
    float* bias16 = att + (size_t)256 * 256 * 192;   // 12,582,912
    float* tbl6   = bias16 + (size_t)6 * 256 * 256;  // 393,216
    short* w1pack = (short*)(tbl6 + 9472);           // 147,456 bf16
    short* w2pack = w1pack + (size_t)768 * 192;      // 147,456 bf16

    hipLaunchKernelGGL(pack_w_k, dim3(288), dim3(64), 0, stream, fc1_w, w1pack, 192);
    hipLaunchKernelGGL(pack_w_k, dim3(288), dim3(64), 0, stream, fc2_w, w2pack, 768);
    hipLaunchKernelGGL(cpb_table_k, dim3(1575), dim3(512), 0, stream, cpb_w1, cpb_b1, cpb_w2, tbl6);
    hipLaunchKernelGGL(bias_k, dim3(1536), dim3(256), 0, stream, tbl6, bias16);
    hipLaunchKernelGGL(qkv_k, dim3(4096), dim3(192), 0, stream, x, qkv_w, qkv_b, qn, kn, vv);
    hipLaunchKernelGGL(attn_k, dim3(6, 256), dim3(128), 0, stream, qn, kn, vv, bias16, logit_scale, att);
    hipLaunchKernelGGL(proj_k, dim3(4096), dim3(192), 0, stream, att, proj_w, proj_b, x, norm1_g, norm1_b, out);
    hipLaunchKernelGGL(mlp_mfma_k, dim3(2048), dim3(256), 0, stream, w1pack, w2pack,
                       fc1_b, fc2_b, norm2_g, norm2_b, out);
}

// Round 3
// 805.705 us; speedup vs baseline: 3.6800x; 1.6765x over previous
//
#include <hip/hip_runtime.h>
#include <math.h>

// Problem constants
// B=2, T=8, H=64, W=64, C=192, WIN=(4,8,8), SHIFT=(2,4,4), HEADS=6, d=32
// N=256 tokens/window, nW=128 windows/batch, B_=256 windows total, HID=768

typedef short short8 __attribute__((ext_vector_type(8)));
typedef float f32x4 __attribute__((ext_vector_type(4)));

__device__ __forceinline__ short f2bf(float f) {
    union { float f; unsigned u; } v; v.f = f;
    unsigned r = v.u + 0x7FFF + ((v.u >> 16) & 1);  // RNE
    return (short)(r >> 16);
}

// ---------------------------------------------------------------- K0: pack fp32 weight (Nout, K) -> bf16 B-fragment order
// frag (nt, kt): lane l holds B[k=(l>>4)*8+j][n=l&15] = W[nt*16+(l&15)][kt*32+(l>>4)*8+j]
__global__ __launch_bounds__(64) void pack_w_k(const float* __restrict__ w,
                                               short* __restrict__ dst, int K) {
    int lane = threadIdx.x;
    int ktn = K >> 5;
    int nt = blockIdx.x / ktn, kt = blockIdx.x % ktn;
    int r = lane & 15, q = lane >> 4;
    const float* src = w + (size_t)(nt * 16 + r) * K + kt * 32 + q * 8;
    short8 v;
#pragma unroll
    for (int j = 0; j < 8; j++) v[j] = f2bf(src[j]);
    ((short8*)dst)[(size_t)blockIdx.x * 64 + lane] = v;
}

// ---------------------------------------------------------------- K1a: CPB MLP table
__global__ __launch_bounds__(512) void cpb_table_k(const float* __restrict__ w1,
                                                   const float* __restrict__ b1,
                                                   const float* __restrict__ w2,
                                                   float* __restrict__ tbl6) {
    __shared__ float red[512];
    int m = blockIdx.x;
    int it = m / 225;
    int ih = (m / 15) % 15;
    int iw = m % 15;
    float r0 = (float)(it - 3) * (8.0f / 3.0f);
    float r1 = (float)(ih - 7) * (8.0f / 7.0f);
    float r2 = (float)(iw - 7) * (8.0f / 7.0f);
    float c0 = (r0 < 0.f ? -1.f : 1.f) * log2f(fabsf(r0) + 1.0f) * (1.0f / 3.0f);
    float c1 = (r1 < 0.f ? -1.f : 1.f) * log2f(fabsf(r1) + 1.0f) * (1.0f / 3.0f);
    float c2 = (r2 < 0.f ? -1.f : 1.f) * log2f(fabsf(r2) + 1.0f) * (1.0f / 3.0f);
    int t = threadIdx.x;
    float hv = fmaxf(0.0f, c0 * w1[3 * t] + c1 * w1[3 * t + 1] + c2 * w1[3 * t + 2] + b1[t]);
    for (int head = 0; head < 6; head++) {
        red[t] = hv * w2[head * 512 + t];
        __syncthreads();
        for (int s = 256; s > 0; s >>= 1) {
            if (t < s) red[t] += red[t + s];
            __syncthreads();
        }
        if (t == 0) tbl6[m * 6 + head] = red[0];
        __syncthreads();
    }
}

// ---------------------------------------------------------------- K1b: bias16[h][i][j] = 16*sigmoid(tbl6[rpi(i,j)][h])
__global__ __launch_bounds__(256) void bias_k(const float* __restrict__ tbl6,
                                              float* __restrict__ bias16) {
    int idx = blockIdx.x * 256 + threadIdx.x;
    int h = idx >> 16;
    int r = idx & 65535;
    int i = r >> 8, j = r & 255;
    int dt = (i >> 6) - (j >> 6) + 3;
    int dh = ((i >> 3) & 7) - ((j >> 3) & 7) + 7;
    int dw = (i & 7) - (j & 7) + 7;
    int rel = dt * 225 + dh * 15 + dw;
    float v = tbl6[rel * 6 + h];
    bias16[idx] = 16.0f / (1.0f + expf(-v));
}

// ---------------------------------------------------------------- K2: QKV via bf16 MFMA + shifted-window gather + q/k normalize
// block=256 (4 waves), 32 tokens/block, grid 2048. 36 n-tiles (q:0-11,k:12-23,v:24-35), 9/wave.
#define ZSTR 388
__global__ __launch_bounds__(256) void qkv_mfma_k(const float* __restrict__ x,
                                                  const short* __restrict__ wqp,
                                                  const float* __restrict__ qkv_b,
                                                  float* __restrict__ qn,
                                                  float* __restrict__ kn,
                                                  float* __restrict__ vv) {
    __shared__ float Z[32 * ZSTR];  // q,k channels 0..383 (49664 B)
    int tid = threadIdx.x, lane = tid & 63, w = tid >> 6;
    int r = lane & 15, q = lane >> 4;
    int b_ = blockIdx.x >> 3, n0 = (blockIdx.x & 7) << 5;
    int b = b_ >> 7, win = b_ & 127;
    int wt = win >> 6, wh = (win >> 3) & 7, ww = win & 7;

    // A fragments straight from global x with roll-gather
    short8 af[2][6];
#pragma unroll
    for (int m = 0; m < 2; m++) {
        int n = n0 + m * 16 + r;
        int t0 = ((wt * 4 + (n >> 6)) + 2) & 7;
        int h0 = ((wh * 8 + ((n >> 3) & 7)) + 4) & 63;
        int w0 = ((ww * 8 + (n & 7)) + 4) & 63;
        const float* src = x + ((size_t)((b * 8 + t0) * 64 + h0) * 64 + w0) * 192 + q * 8;
#pragma unroll
        for (int kt = 0; kt < 6; kt++) {
            float4 x0 = *(const float4*)(src + kt * 32);
            float4 x1 = *(const float4*)(src + kt * 32 + 4);
            short8 v;
            v[0] = f2bf(x0.x); v[1] = f2bf(x0.y); v[2] = f2bf(x0.z); v[3] = f2bf(x0.w);
            v[4] = f2bf(x1.x); v[5] = f2bf(x1.y); v[6] = f2bf(x1.z); v[7] = f2bf(x1.w);
            af[m][kt] = v;
        }
    }

    for (int ntl = 0; ntl < 9; ntl++) {
        int nt = w * 9 + ntl;
        float bias = qkv_b[nt * 16 + r];
        short8 bfr[6];
#pragma unroll
        for (int kt = 0; kt < 6; kt++)
            bfr[kt] = ((const short8*)wqp)[(size_t)(nt * 6 + kt) * 64 + lane];
        f32x4 a0 = {bias, bias, bias, bias};
        f32x4 a1 = {bias, bias, bias, bias};
#pragma unroll
        for (int kt = 0; kt < 6; kt++) {
            a0 = __builtin_amdgcn_mfma_f32_16x16x32_bf16(af[0][kt], bfr[kt], a0, 0, 0, 0);
            a1 = __builtin_amdgcn_mfma_f32_16x16x32_bf16(af[1][kt], bfr[kt], a1, 0, 0, 0);
        }
        int col = nt * 16 + r;
        if (nt < 24) {  // q,k -> LDS for normalization
#pragma unroll
            for (int reg = 0; reg < 4; reg++) {
                Z[(q * 4 + reg) * ZSTR + col] = a0[reg];
                Z[(16 + q * 4 + reg) * ZSTR + col] = a1[reg];
            }
        } else {  // v -> global directly (C/D layout scatter, 64B segments)
            int ch = col - 384;
            int h = ch >> 5, d = ch & 31;
            float* vb = vv + ((size_t)(b_ * 6 + h) * 256 + n0) * 32 + d;
#pragma unroll
            for (int reg = 0; reg < 4; reg++) {
                vb[(size_t)(q * 4 + reg) * 32] = a0[reg];
                vb[(size_t)(16 + q * 4 + reg) * 32] = a1[reg];
            }
        }
    }
    __syncthreads();
    // normalize q/k: 32 tokens x 12 rows (6 q-heads + 6 k-heads)
    for (int rw = tid; rw < 384; rw += 256) {
        int token = rw / 12, rr = rw - token * 12;
        int isq = rr < 6 ? 1 : 0;
        int h = isq ? rr : rr - 6;
        const float* rp = &Z[token * ZSTR + rr * 32];
        float ss = 0.f;
#pragma unroll
        for (int d = 0; d < 32; d++) ss += rp[d] * rp[d];
        float inv = 1.0f / fmaxf(sqrtf(ss), 1e-12f);
        float* dst = (isq ? qn : kn) + ((size_t)(b_ * 6 + h) * 256 + n0 + token) * 32;
#pragma unroll
        for (int d = 0; d < 32; d++) dst[d] = rp[d] * inv;
    }
}

// ---------------------------------------------------------------- K3: cosine attention per (window, head)
__global__ __launch_bounds__(128) void attn_k(const float* __restrict__ qn,
                                              const float* __restrict__ kn,
                                              const float* __restrict__ vv,
                                              const float* __restrict__ bias16,
                                              const float* __restrict__ logit_scale,
                                              float* __restrict__ att) {
    __shared__ float kl[256 * 32];
    __shared__ float vl[256 * 32];
    int tid = threadIdx.x;
    int h = blockIdx.x;
    int b_ = blockIdx.y;
    const float4* kp = (const float4*)(kn + ((size_t)(b_ * 6 + h) * 256) * 32);
    const float4* vp = (const float4*)(vv + ((size_t)(b_ * 6 + h) * 256) * 32);
    float4* kl4 = (float4*)kl;
    float4* vl4 = (float4*)vl;
    for (int idx = tid; idx < 2048; idx += 128) {
        kl4[idx] = kp[idx];
        vl4[idx] = vp[idx];
    }
    float scale = __expf(fminf(logit_scale[h], 4.6051702f));
    int win = b_ & 127;
    int wt4 = (win >> 6) * 4, wh8 = ((win >> 3) & 7) * 8, ww8 = (win & 7) * 8;
    auto region = [&](int n) {
        int ts = wt4 + (n >> 6), hs = wh8 + ((n >> 3) & 7), wsv = ww8 + (n & 7);
        int rt = ts < 4 ? 0 : (ts < 6 ? 1 : 2);
        int rh = hs < 56 ? 0 : (hs < 60 ? 1 : 2);
        int rw = wsv < 56 ? 0 : (wsv < 60 ? 1 : 2);
        return rt * 9 + rh * 3 + rw;
    };
    int i0 = tid, i1 = tid + 128;
    int ri0 = region(i0), ri1 = region(i1);
    float q0[32], q1[32];
    {
        const float4* q0p = (const float4*)(qn + ((size_t)(b_ * 6 + h) * 256 + i0) * 32);
        const float4* q1p = (const float4*)(qn + ((size_t)(b_ * 6 + h) * 256 + i1) * 32);
#pragma unroll
        for (int d4 = 0; d4 < 8; d4++) {
            float4 a = q0p[d4];
            q0[d4 * 4 + 0] = a.x * scale; q0[d4 * 4 + 1] = a.y * scale;
            q0[d4 * 4 + 2] = a.z * scale; q0[d4 * 4 + 3] = a.w * scale;
            float4 bq = q1p[d4];
            q1[d4 * 4 + 0] = bq.x * scale; q1[d4 * 4 + 1] = bq.y * scale;
            q1[d4 * 4 + 2] = bq.z * scale; q1[d4 * 4 + 3] = bq.w * scale;
        }
    }
    __syncthreads();
    const float* bias0 = bias16 + ((size_t)h << 16) + (size_t)i0 * 256;
    const float* bias1 = bias16 + ((size_t)h << 16) + (size_t)i1 * 256;
    float M = scale + 16.0f;
    float l0 = 0.f, l1 = 0.f;
    float a0[32], a1[32];
#pragma unroll
    for (int d = 0; d < 32; d++) { a0[d] = 0.f; a1[d] = 0.f; }
    for (int j = 0; j < 256; j++) {
        float d0 = 0.f, d1 = 0.f;
#pragma unroll
        for (int d4 = 0; d4 < 8; d4++) {
            float4 kv = kl4[j * 8 + d4];
            d0 += q0[d4 * 4] * kv.x + q0[d4 * 4 + 1] * kv.y + q0[d4 * 4 + 2] * kv.z + q0[d4 * 4 + 3] * kv.w;
            d1 += q1[d4 * 4] * kv.x + q1[d4 * 4 + 1] * kv.y + q1[d4 * 4 + 2] * kv.z + q1[d4 * 4 + 3] * kv.w;
        }
        int rgj = region(j);
        float s0 = d0 + bias0[j] + (rgj == ri0 ? 0.0f : -100.0f);
        float s1 = d1 + bias1[j] + (rgj == ri1 ? 0.0f : -100.0f);
        float p0 = __expf(s0 - M);
        float p1 = __expf(s1 - M);
        l0 += p0; l1 += p1;
#pragma unroll
        for (int d4 = 0; d4 < 8; d4++) {
            float4 vq = vl4[j * 8 + d4];
            a0[d4 * 4 + 0] += p0 * vq.x; a0[d4 * 4 + 1] += p0 * vq.y;
            a0[d4 * 4 + 2] += p0 * vq.z; a0[d4 * 4 + 3] += p0 * vq.w;
            a1[d4 * 4 + 0] += p1 * vq.x; a1[d4 * 4 + 1] += p1 * vq.y;
            a1[d4 * 4 + 2] += p1 * vq.z; a1[d4 * 4 + 3] += p1 * vq.w;
        }
    }
    float inv0 = 1.0f / l0, inv1 = 1.0f / l1;
    float4* o0 = (float4*)(att + ((size_t)b_ * 256 + i0) * 192 + h * 32);
    float4* o1 = (float4*)(att + ((size_t)b_ * 256 + i1) * 192 + h * 32);
#pragma unroll
    for (int d4 = 0; d4 < 8; d4++) {
        o0[d4] = make_float4(a0[d4 * 4] * inv0, a0[d4 * 4 + 1] * inv0, a0[d4 * 4 + 2] * inv0, a0[d4 * 4 + 3] * inv0);
        o1[d4] = make_float4(a1[d4 * 4] * inv1, a1[d4 * 4 + 1] * inv1, a1[d4 * 4 + 2] * inv1, a1[d4 * 4 + 3] * inv1);
    }
}

// ---------------------------------------------------------------- K4: out-proj via bf16 MFMA + LN + roll-scatter + residual
// block=256 (4 waves), 32 tokens/block, grid 2048. 12 n-tiles, 3/wave.
__global__ __launch_bounds__(256) void proj_mfma_k(const float* __restrict__ att,
                                                   const short* __restrict__ wpp,
                                                   const float* __restrict__ proj_b,
                                                   const float* __restrict__ x,
                                                   const float* __restrict__ g1,
                                                   const float* __restrict__ b1n,
                                                   float* __restrict__ out) {
    __shared__ float Z[32 * 196];  // 25088 B
    __shared__ float ps[32][8];
    __shared__ float pss[32][8];
    __shared__ float mean_s[32], inv_s[32];
    int tid = threadIdx.x, lane = tid & 63, w = tid >> 6;
    int r = lane & 15, q = lane >> 4;
    int b_ = blockIdx.x >> 3, n0 = (blockIdx.x & 7) << 5;

    short8 af[2][6];
#pragma unroll
    for (int m = 0; m < 2; m++) {
        const float* src = att + ((size_t)b_ * 256 + n0 + m * 16 + r) * 192 + q * 8;
#pragma unroll
        for (int kt = 0; kt < 6; kt++) {
            float4 x0 = *(const float4*)(src + kt * 32);
            float4 x1 = *(const float4*)(src + kt * 32 + 4);
            short8 v;
            v[0] = f2bf(x0.x); v[1] = f2bf(x0.y); v[2] = f2bf(x0.z); v[3] = f2bf(x0.w);
            v[4] = f2bf(x1.x); v[5] = f2bf(x1.y); v[6] = f2bf(x1.z); v[7] = f2bf(x1.w);
            af[m][kt] = v;
        }
    }
    for (int ntl = 0; ntl < 3; ntl++) {
        int nt = w * 3 + ntl;
        float bias = proj_b[nt * 16 + r];
        short8 bfr[6];
#pragma unroll
        for (int kt = 0; kt < 6; kt++)
            bfr[kt] = ((const short8*)wpp)[(size_t)(nt * 6 + kt) * 64 + lane];
        f32x4 a0 = {bias, bias, bias, bias};
        f32x4 a1 = {bias, bias, bias, bias};
#pragma unroll
        for (int kt = 0; kt < 6; kt++) {
            a0 = __builtin_amdgcn_mfma_f32_16x16x32_bf16(af[0][kt], bfr[kt], a0, 0, 0, 0);
            a1 = __builtin_amdgcn_mfma_f32_16x16x32_bf16(af[1][kt], bfr[kt], a1, 0, 0, 0);
        }
        int col = nt * 16 + r;
#pragma unroll
        for (int reg = 0; reg < 4; reg++) {
            Z[(q * 4 + reg) * 196 + col] = a0[reg];
            Z[(16 + q * 4 + reg) * 196 + col] = a1[reg];
        }
    }
    __syncthreads();
    {
        int token = tid >> 3, part = tid & 7;
        float s = 0.f, ss = 0.f;
        const float* zr = &Z[token * 196 + part * 24];
#pragma unroll
        for (int c = 0; c < 24; c++) { float v = zr[c]; s += v; ss += v * v; }
        ps[token][part] = s; pss[token][part] = ss;
    }
    __syncthreads();
    if (tid < 32) {
        float s = 0.f, ss = 0.f;
#pragma unroll
        for (int p = 0; p < 8; p++) { s += ps[tid][p]; ss += pss[tid][p]; }
        float mean = s * (1.0f / 192.0f);
        float var = ss * (1.0f / 192.0f) - mean * mean;
        mean_s[tid] = mean;
        inv_s[tid] = 1.0f / sqrtf(var + 1e-5f);
    }
    __syncthreads();
    int b = b_ >> 7, win = b_ & 127;
    int wt = win >> 6, wh = (win >> 3) & 7, ww = win & 7;
    for (int idx = tid; idx < 6144; idx += 256) {
        int token = idx / 192;
        int ch = idx - token * 192;
        int n = n0 + token;
        int t0 = ((wt * 4 + (n >> 6)) + 2) & 7;
        int h0 = ((wh * 8 + ((n >> 3) & 7)) + 4) & 63;
        int w0 = ((ww * 8 + (n & 7)) + 4) & 63;
        size_t gb = ((size_t)((b * 8 + t0) * 64 + h0) * 64 + w0) * 192;
        float v = (Z[token * 196 + ch] - mean_s[token]) * inv_s[token] * g1[ch] + b1n[ch];
        out[gb + ch] = x[gb + ch] + v;
    }
}

// ---------------------------------------------------------------- K5: MLP via bf16 MFMA, fused fc1+GELU+fc2+LN+residual
#define HSTR 776
__global__ __launch_bounds__(256) void mlp_mfma_k(const short* __restrict__ w1p,
                                                  const short* __restrict__ w2p,
                                                  const float* __restrict__ fc1_b,
                                                  const float* __restrict__ fc2_b,
                                                  const float* __restrict__ g2,
                                                  const float* __restrict__ b2,
                                                  float* __restrict__ out) {
    __shared__ short Hs[32 * HSTR];      // 49664 B; reused as Z fp32 [32][193]
    __shared__ float ps[32][8];
    __shared__ float pss[32][8];
    __shared__ float mean_s[32], inv_s[32];
    int tid = threadIdx.x;
    int lane = tid & 63, w = tid >> 6;
    int r = lane & 15, q = lane >> 4;
    size_t tok0 = (size_t)blockIdx.x * 32;

    short8 af[2][6];
#pragma unroll
    for (int m = 0; m < 2; m++)
#pragma unroll
        for (int kt = 0; kt < 6; kt++) {
            const float* src = out + (tok0 + m * 16 + r) * 192 + kt * 32 + q * 8;
            float4 x0 = *(const float4*)src;
            float4 x1 = *(const float4*)(src + 4);
            short8 v;
            v[0] = f2bf(x0.x); v[1] = f2bf(x0.y); v[2] = f2bf(x0.z); v[3] = f2bf(x0.w);
            v[4] = f2bf(x1.x); v[5] = f2bf(x1.y); v[6] = f2bf(x1.z); v[7] = f2bf(x1.w);
            af[m][kt] = v;
        }

    for (int ntl = 0; ntl < 12; ntl++) {
        int nt = w * 12 + ntl;
        float bias = fc1_b[nt * 16 + r];
        short8 bfr[6];
#pragma unroll
        for (int kt = 0; kt < 6; kt++)
            bfr[kt] = ((const short8*)w1p)[(size_t)(nt * 6 + kt) * 64 + lane];
        f32x4 acc0 = {bias, bias, bias, bias};
        f32x4 acc1 = {bias, bias, bias, bias};
#pragma unroll
        for (int kt = 0; kt < 6; kt++) {
            acc0 = __builtin_amdgcn_mfma_f32_16x16x32_bf16(af[0][kt], bfr[kt], acc0, 0, 0, 0);
            acc1 = __builtin_amdgcn_mfma_f32_16x16x32_bf16(af[1][kt], bfr[kt], acc1, 0, 0, 0);
        }
        int col = nt * 16 + r;
#pragma unroll
        for (int reg = 0; reg < 4; reg++) {
            float u0 = acc0[reg];
            float u1 = acc1[reg];
            float gl0 = 0.5f * u0 * (1.0f + erff(u0 * 0.70710678118654752f));
            float gl1 = 0.5f * u1 * (1.0f + erff(u1 * 0.70710678118654752f));
            Hs[(q * 4 + reg) * HSTR + col] = f2bf(gl0);
            Hs[(16 + q * 4 + reg) * HSTR + col] = f2bf(gl1);
        }
    }
    __syncthreads();

    f32x4 acc2[2][3];
#pragma unroll
    for (int m = 0; m < 2; m++)
#pragma unroll
        for (int n = 0; n < 3; n++) acc2[m][n] = (f32x4){0.f, 0.f, 0.f, 0.f};
    for (int kk = 0; kk < 24; kk++) {
        short8 a0 = *(const short8*)&Hs[(r) * HSTR + kk * 32 + q * 8];
        short8 a1 = *(const short8*)&Hs[(16 + r) * HSTR + kk * 32 + q * 8];
#pragma unroll
        for (int n = 0; n < 3; n++) {
            int nt = w * 3 + n;
            short8 bfr = ((const short8*)w2p)[(size_t)(nt * 24 + kk) * 64 + lane];
            acc2[0][n] = __builtin_amdgcn_mfma_f32_16x16x32_bf16(a0, bfr, acc2[0][n], 0, 0, 0);
            acc2[1][n] = __builtin_amdgcn_mfma_f32_16x16x32_bf16(a1, bfr, acc2[1][n], 0, 0, 0);
        }
    }
    __syncthreads();
    float* Z = (float*)Hs;
#pragma unroll
    for (int m = 0; m < 2; m++)
#pragma unroll
        for (int n = 0; n < 3; n++) {
            int nt = w * 3 + n;
            int col = nt * 16 + r;
            float bias2 = fc2_b[col];
#pragma unroll
            for (int reg = 0; reg < 4; reg++)
                Z[(m * 16 + q * 4 + reg) * 193 + col] = acc2[m][n][reg] + bias2;
        }
    __syncthreads();

    {
        int token = tid >> 3, part = tid & 7;
        float s = 0.f, ss = 0.f;
        const float* zr = &Z[token * 193 + part * 24];
#pragma unroll
        for (int c = 0; c < 24; c++) { float v = zr[c]; s += v; ss += v * v; }
        ps[token][part] = s; pss[token][part] = ss;
    }
    __syncthreads();
    if (tid < 32) {
        float s = 0.f, ss = 0.f;
#pragma unroll
        for (int p = 0; p < 8; p++) { s += ps[tid][p]; ss += pss[tid][p]; }
        float mean = s * (1.0f / 192.0f);
        float var = ss * (1.0f / 192.0f) - mean * mean;
        mean_s[tid] = mean;
        inv_s[tid] = 1.0f / sqrtf(var + 1e-5f);
    }
    __syncthreads();
    for (int rep = 0; rep < 24; rep++) {
        int idx = rep * 256 + tid;
        int token = idx / 192;
        int ch = idx - token * 192;
        float v = (Z[token * 193 + ch] - mean_s[token]) * inv_s[token] * g2[ch] + b2[ch];
        size_t gi = (tok0 + token) * 192 + ch;
        out[gi] = out[gi] + v;
    }
}

// ---------------------------------------------------------------- launch
extern "C" void kernel_launch(void* const* d_in, const int* in_sizes, int n_in,
                              void* d_out, int out_size, void* d_ws, size_t ws_size,
                              hipStream_t stream) {
    const float* x           = (const float*)d_in[0];
    const float* qkv_w       = (const float*)d_in[1];
    const float* qkv_b       = (const float*)d_in[2];
    const float* proj_w      = (const float*)d_in[3];
    const float* proj_b      = (const float*)d_in[4];
    const float* cpb_w1      = (const float*)d_in[5];
    const float* cpb_b1      = (const float*)d_in[6];
    const float* cpb_w2      = (const float*)d_in[7];
    const float* logit_scale = (const float*)d_in[8];
    const float* norm1_g     = (const float*)d_in[9];
    const float* norm1_b     = (const float*)d_in[10];
    const float* norm2_g     = (const float*)d_in[11];
    const float* norm2_b     = (const float*)d_in[12];
    const float* fc1_w       = (const float*)d_in[13];
    const float* fc1_b       = (const float*)d_in[14];
    const float* fc2_w       = (const float*)d_in[15];
    const float* fc2_b       = (const float*)d_in[16];
    float* out = (float*)d_out;

    float* ws = (float*)d_ws;
    const size_t QKVE = (size_t)256 * 6 * 256 * 32;  // 12,582,912 per tensor
    float* qn     = ws;
    float* kn     = qn + QKVE;
    float* vv     = kn + QKVE;
    float* att    = vv + QKVE;
    float* bias16 = att + (size_t)256 * 256 * 192;   // 12,582,912
    float* tbl6   = bias16 + (size_t)6 * 256 * 256;  // 393,216
    short* w1pack = (short*)(tbl6 + 9472);           // fc1: 147,456 bf16
    short* w2pack = w1pack + (size_t)768 * 192;      // fc2: 147,456 bf16
    short* wqpack = w2pack + (size_t)192 * 768;      // qkv: 110,592 bf16
    short* wppack = wqpack + (size_t)576 * 192;      // proj: 36,864 bf16

    hipLaunchKernelGGL(pack_w_k, dim3(288), dim3(64), 0, stream, fc1_w, w1pack, 192);
    hipLaunchKernelGGL(pack_w_k, dim3(288), dim3(64), 0, stream, fc2_w, w2pack, 768);
    hipLaunchKernelGGL(pack_w_k, dim3(216), dim3(64), 0, stream, qkv_w, wqpack, 192);
    hipLaunchKernelGGL(pack_w_k, dim3(72), dim3(64), 0, stream, proj_w, wppack, 192);
    hipLaunchKernelGGL(cpb_table_k, dim3(1575), dim3(512), 0, stream, cpb_w1, cpb_b1, cpb_w2, tbl6);
    hipLaunchKernelGGL(bias_k, dim3(1536), dim3(256), 0, stream, tbl6, bias16);
    hipLaunchKernelGGL(qkv_mfma_k, dim3(2048), dim3(256), 0, stream, x, wqpack, qkv_b, qn, kn, vv);
    hipLaunchKernelGGL(attn_k, dim3(6, 256), dim3(128), 0, stream, qn, kn, vv, bias16, logit_scale, att);
    hipLaunchKernelGGL(proj_mfma_k, dim3(2048), dim3(256), 0, stream, att, wppack, proj_b, x, norm1_g, norm1_b, out);
    hipLaunchKernelGGL(mlp_mfma_k, dim3(2048), dim3(256), 0, stream, w1pack, w2pack,
                       fc1_b, fc2_b, norm2_g, norm2_b, out);
}

// Round 4
// 440.563 us; speedup vs baseline: 6.7300x; 1.8288x over previous
//
#include <hip/hip_runtime.h>
#include <math.h>

// Problem constants
// B=2, T=8, H=64, W=64, C=192, WIN=(4,8,8), SHIFT=(2,4,4), HEADS=6, d=32
// N=256 tokens/window, nW=128 windows/batch, B_=256 windows total, HID=768

typedef short short8 __attribute__((ext_vector_type(8)));
typedef short short4v __attribute__((ext_vector_type(4)));
typedef float f32x4 __attribute__((ext_vector_type(4)));

__device__ __forceinline__ short f2bf(float f) {
    union { float f; unsigned u; } v; v.f = f;
    unsigned r = v.u + 0x7FFF + ((v.u >> 16) & 1);  // RNE
    return (short)(r >> 16);
}

// ---------------------------------------------------------------- K0: pack fp32 weight (Nout, K) -> bf16 B-fragment order
// frag (nt, kt): lane l holds B[k=(l>>4)*8+j][n=l&15] = W[nt*16+(l&15)][kt*32+(l>>4)*8+j]
__global__ __launch_bounds__(64) void pack_w_k(const float* __restrict__ w,
                                               short* __restrict__ dst, int K) {
    int lane = threadIdx.x;
    int ktn = K >> 5;
    int nt = blockIdx.x / ktn, kt = blockIdx.x % ktn;
    int r = lane & 15, q = lane >> 4;
    const float* src = w + (size_t)(nt * 16 + r) * K + kt * 32 + q * 8;
    short8 v;
#pragma unroll
    for (int j = 0; j < 8; j++) v[j] = f2bf(src[j]);
    ((short8*)dst)[(size_t)blockIdx.x * 64 + lane] = v;
}

// ---------------------------------------------------------------- K1a: CPB MLP table
__global__ __launch_bounds__(512) void cpb_table_k(const float* __restrict__ w1,
                                                   const float* __restrict__ b1,
                                                   const float* __restrict__ w2,
                                                   float* __restrict__ tbl6) {
    __shared__ float red[512];
    int m = blockIdx.x;
    int it = m / 225;
    int ih = (m / 15) % 15;
    int iw = m % 15;
    float r0 = (float)(it - 3) * (8.0f / 3.0f);
    float r1 = (float)(ih - 7) * (8.0f / 7.0f);
    float r2 = (float)(iw - 7) * (8.0f / 7.0f);
    float c0 = (r0 < 0.f ? -1.f : 1.f) * log2f(fabsf(r0) + 1.0f) * (1.0f / 3.0f);
    float c1 = (r1 < 0.f ? -1.f : 1.f) * log2f(fabsf(r1) + 1.0f) * (1.0f / 3.0f);
    float c2 = (r2 < 0.f ? -1.f : 1.f) * log2f(fabsf(r2) + 1.0f) * (1.0f / 3.0f);
    int t = threadIdx.x;
    float hv = fmaxf(0.0f, c0 * w1[3 * t] + c1 * w1[3 * t + 1] + c2 * w1[3 * t + 2] + b1[t]);
    for (int head = 0; head < 6; head++) {
        red[t] = hv * w2[head * 512 + t];
        __syncthreads();
        for (int s = 256; s > 0; s >>= 1) {
            if (t < s) red[t] += red[t + s];
            __syncthreads();
        }
        if (t == 0) tbl6[m * 6 + head] = red[0];
        __syncthreads();
    }
}

// ---------------------------------------------------------------- K1b: biasT[h][key][query] = 16*sigmoid(cpb(query,key))  (TRANSPOSED)
__global__ __launch_bounds__(256) void bias_k(const float* __restrict__ tbl6,
                                              float* __restrict__ biasT) {
    int idx = blockIdx.x * 256 + threadIdx.x;  // h*65536 + key*256 + query
    int h = idx >> 16;
    int rem = idx & 65535;
    int jj = rem >> 8, ii = rem & 255;  // jj = key, ii = query
    int dt = (ii >> 6) - (jj >> 6) + 3;
    int dh = ((ii >> 3) & 7) - ((jj >> 3) & 7) + 7;
    int dw = (ii & 7) - (jj & 7) + 7;
    int rel = dt * 225 + dh * 15 + dw;
    float v = tbl6[rel * 6 + h];
    biasT[idx] = 16.0f / (1.0f + expf(-v));
}

// ---------------------------------------------------------------- K2: QKV via bf16 MFMA + shifted-window gather + q/k normalize
// Outputs: qbf/kbf bf16 [b_,h,256,32] normalized; vtb bf16 [b_,h,32,256] (V transposed).
#define ZSTR 388
__global__ __launch_bounds__(256) void qkv_mfma_k(const float* __restrict__ x,
                                                  const short* __restrict__ wqp,
                                                  const float* __restrict__ qkv_b,
                                                  short* __restrict__ qbf,
                                                  short* __restrict__ kbf,
                                                  short* __restrict__ vtb) {
    __shared__ float Z[32 * ZSTR];  // q,k channels 0..383 (49664 B)
    int tid = threadIdx.x, lane = tid & 63, w = tid >> 6;
    int r = lane & 15, q = lane >> 4;
    int b_ = blockIdx.x >> 3, n0 = (blockIdx.x & 7) << 5;
    int b = b_ >> 7, win = b_ & 127;
    int wt = win >> 6, wh = (win >> 3) & 7, ww = win & 7;

    // A fragments straight from global x with roll-gather
    short8 af[2][6];
#pragma unroll
    for (int m = 0; m < 2; m++) {
        int n = n0 + m * 16 + r;
        int t0 = ((wt * 4 + (n >> 6)) + 2) & 7;
        int h0 = ((wh * 8 + ((n >> 3) & 7)) + 4) & 63;
        int w0 = ((ww * 8 + (n & 7)) + 4) & 63;
        const float* src = x + ((size_t)((b * 8 + t0) * 64 + h0) * 64 + w0) * 192 + q * 8;
#pragma unroll
        for (int kt = 0; kt < 6; kt++) {
            float4 x0 = *(const float4*)(src + kt * 32);
            float4 x1 = *(const float4*)(src + kt * 32 + 4);
            short8 v;
            v[0] = f2bf(x0.x); v[1] = f2bf(x0.y); v[2] = f2bf(x0.z); v[3] = f2bf(x0.w);
            v[4] = f2bf(x1.x); v[5] = f2bf(x1.y); v[6] = f2bf(x1.z); v[7] = f2bf(x1.w);
            af[m][kt] = v;
        }
    }

    for (int ntl = 0; ntl < 9; ntl++) {
        int nt = w * 9 + ntl;
        float bias = qkv_b[nt * 16 + r];
        short8 bfr[6];
#pragma unroll
        for (int kt = 0; kt < 6; kt++)
            bfr[kt] = ((const short8*)wqp)[(size_t)(nt * 6 + kt) * 64 + lane];
        f32x4 a0 = {bias, bias, bias, bias};
        f32x4 a1 = {bias, bias, bias, bias};
#pragma unroll
        for (int kt = 0; kt < 6; kt++) {
            a0 = __builtin_amdgcn_mfma_f32_16x16x32_bf16(af[0][kt], bfr[kt], a0, 0, 0, 0);
            a1 = __builtin_amdgcn_mfma_f32_16x16x32_bf16(af[1][kt], bfr[kt], a1, 0, 0, 0);
        }
        int col = nt * 16 + r;
        if (nt < 24) {  // q,k -> LDS for normalization
#pragma unroll
            for (int reg = 0; reg < 4; reg++) {
                Z[(q * 4 + reg) * ZSTR + col] = a0[reg];
                Z[(16 + q * 4 + reg) * ZSTR + col] = a1[reg];
            }
        } else {  // v -> global transposed bf16: vtb[(b_*6+h)*32+d][key]
            int ch = col - 384;
            int hh = ch >> 5, dd = ch & 31;
            short* vb = vtb + ((size_t)(b_ * 6 + hh) * 32 + dd) * 256 + n0;
            short4v p0, p1;
#pragma unroll
            for (int reg = 0; reg < 4; reg++) { p0[reg] = f2bf(a0[reg]); p1[reg] = f2bf(a1[reg]); }
            *(short4v*)(vb + q * 4) = p0;        // keys n0 + q*4 + reg
            *(short4v*)(vb + 16 + q * 4) = p1;   // keys n0 + 16 + q*4 + reg
        }
    }
    __syncthreads();
    // normalize q/k: 32 tokens x 12 rows (6 q-heads + 6 k-heads), write bf16
    for (int rw = tid; rw < 384; rw += 256) {
        int token = rw / 12, rr = rw - token * 12;
        int isq = rr < 6 ? 1 : 0;
        int h = isq ? rr : rr - 6;
        const float* rp = &Z[token * ZSTR + rr * 32];
        float ss = 0.f;
#pragma unroll
        for (int d = 0; d < 32; d++) ss += rp[d] * rp[d];
        float inv = 1.0f / fmaxf(sqrtf(ss), 1e-12f);
        short* dst = (isq ? qbf : kbf) + ((size_t)(b_ * 6 + h) * 256 + n0 + token) * 32;
#pragma unroll
        for (int d8 = 0; d8 < 4; d8++) {
            short8 v;
#pragma unroll
            for (int j = 0; j < 8; j++) v[j] = f2bf(rp[d8 * 8 + j] * inv);
            *(short8*)(dst + d8 * 8) = v;
        }
    }
}

// ---------------------------------------------------------------- K3: flash attention via bf16 MFMA, one block per (window, head)
// block=256 (4 waves); wave w owns queries [w*64, w*64+64). 8 steps of 32 keys.
#define KSTR 40
#define VSTR 264
#define PSTR 40
__global__ __launch_bounds__(256) void attn_mfma_k(const short* __restrict__ qbf,
                                                   const short* __restrict__ kbf,
                                                   const short* __restrict__ vtb,
                                                   const float* __restrict__ biasT,
                                                   const float* __restrict__ logit_scale,
                                                   float* __restrict__ att) {
    __shared__ short Ks[256 * KSTR];      // 20480 B
    __shared__ short Vs[32 * VSTR];       // 16896 B
    __shared__ short Ps[4][16 * PSTR];    // 5120 B (wave-private P tiles)
    int tid = threadIdx.x, lane = tid & 63, w = tid >> 6;
    int r = lane & 15, q = lane >> 4;
    int b_ = blockIdx.x / 6, h = blockIdx.x % 6;
    size_t base = (size_t)(b_ * 6 + h) * 8192;

    // stage K rows and V^T rows into LDS (bf16, padded strides)
    const short8* kg = (const short8*)(kbf + base);
    const short8* vg = (const short8*)(vtb + base);
    for (int i = tid; i < 1024; i += 256) {
        short8 kv = kg[i];
        *(short8*)&Ks[(i >> 2) * KSTR + (i & 3) * 8] = kv;
        short8 vv = vg[i];
        *(short8*)&Vs[(i >> 5) * VSTR + (i & 31) * 8] = vv;
    }

    // Q A-fragments (4 m-tiles per wave)
    short8 qf[4];
#pragma unroll
    for (int mt = 0; mt < 4; mt++)
        qf[mt] = *(const short8*)(qbf + base + (size_t)(w * 64 + mt * 16 + r) * 32 + q * 8);

    float scale = __expf(fminf(logit_scale[h], 4.6051702f));
    float M = scale + 16.0f;
    int win = b_ & 127;
    int wt4 = (win >> 6) * 4, wh8 = ((win >> 3) & 7) * 8, ww8 = (win & 7) * 8;
    auto region = [&](int n) {
        int ts = wt4 + (n >> 6), hs = wh8 + ((n >> 3) & 7), wsv = ww8 + (n & 7);
        int rt = ts < 4 ? 0 : (ts < 6 ? 1 : 2);
        int rh = hs < 56 ? 0 : (hs < 60 ? 1 : 2);
        int rw = wsv < 56 ? 0 : (wsv < 60 ? 1 : 2);
        return rt * 9 + rh * 3 + rw;
    };
    int rowreg[4][4];  // region of each owned query row (C/D row = q*4+reg)
#pragma unroll
    for (int mt = 0; mt < 4; mt++)
#pragma unroll
        for (int reg = 0; reg < 4; reg++)
            rowreg[mt][reg] = region(w * 64 + mt * 16 + q * 4 + reg);

    f32x4 O[4][2];
    float lp[4][4];
#pragma unroll
    for (int mt = 0; mt < 4; mt++) {
        O[mt][0] = (f32x4){0.f, 0.f, 0.f, 0.f};
        O[mt][1] = (f32x4){0.f, 0.f, 0.f, 0.f};
#pragma unroll
        for (int reg = 0; reg < 4; reg++) lp[mt][reg] = 0.f;
    }
    __syncthreads();

    const float* bh = biasT + ((size_t)h << 16);
    for (int s = 0; s < 8; s++) {
        // K B-frags (keys s*32 + jt*16 + r), V B-frags (d-tiles 0,1)
        short8 kf0 = *(const short8*)&Ks[(s * 32 + r) * KSTR + q * 8];
        short8 kf1 = *(const short8*)&Ks[(s * 32 + 16 + r) * KSTR + q * 8];
        short8 vf0 = *(const short8*)&Vs[r * VSTR + s * 32 + q * 8];
        short8 vf1 = *(const short8*)&Vs[(16 + r) * VSTR + s * 32 + q * 8];
        int cr0 = region(s * 32 + r);
        int cr1 = region(s * 32 + 16 + r);
#pragma unroll
        for (int mt = 0; mt < 4; mt++) {
            f32x4 s0 = {0.f, 0.f, 0.f, 0.f};
            f32x4 s1 = {0.f, 0.f, 0.f, 0.f};
            s0 = __builtin_amdgcn_mfma_f32_16x16x32_bf16(qf[mt], kf0, s0, 0, 0, 0);
            s1 = __builtin_amdgcn_mfma_f32_16x16x32_bf16(qf[mt], kf1, s1, 0, 0, 0);
            int qcol = w * 64 + mt * 16 + q * 4;
            float4 b0 = *(const float4*)(bh + (size_t)(s * 32 + r) * 256 + qcol);
            float4 b1 = *(const float4*)(bh + (size_t)(s * 32 + 16 + r) * 256 + qcol);
#pragma unroll
            for (int reg = 0; reg < 4; reg++) {
                float bb0 = (reg == 0 ? b0.x : reg == 1 ? b0.y : reg == 2 ? b0.z : b0.w);
                float bb1 = (reg == 0 ? b1.x : reg == 1 ? b1.y : reg == 2 ? b1.z : b1.w);
                float v0 = s0[reg] * scale + bb0 + (cr0 == rowreg[mt][reg] ? 0.f : -100.f) - M;
                float v1 = s1[reg] * scale + bb1 + (cr1 == rowreg[mt][reg] ? 0.f : -100.f) - M;
                float p0 = __expf(v0);
                float p1 = __expf(v1);
                lp[mt][reg] += p0 + p1;
                Ps[w][(q * 4 + reg) * PSTR + r] = f2bf(p0);
                Ps[w][(q * 4 + reg) * PSTR + 16 + r] = f2bf(p1);
            }
            // read back as A-frag (wave-internal RAW; compiler inserts lgkmcnt)
            short8 pa = *(const short8*)&Ps[w][r * PSTR + q * 8];
            O[mt][0] = __builtin_amdgcn_mfma_f32_16x16x32_bf16(pa, vf0, O[mt][0], 0, 0, 0);
            O[mt][1] = __builtin_amdgcn_mfma_f32_16x16x32_bf16(pa, vf1, O[mt][1], 0, 0, 0);
        }
    }

    // reduce row sums across the 16 r-lanes (bits 0..3 of lane)
#pragma unroll
    for (int mt = 0; mt < 4; mt++)
#pragma unroll
        for (int reg = 0; reg < 4; reg++) {
            float v = lp[mt][reg];
            v += __shfl_xor(v, 1);
            v += __shfl_xor(v, 2);
            v += __shfl_xor(v, 4);
            v += __shfl_xor(v, 8);
            lp[mt][reg] = 1.0f / v;
        }
    // write O (C/D layout): att[(b_*256+query)*192 + h*32 + d]
#pragma unroll
    for (int mt = 0; mt < 4; mt++)
#pragma unroll
        for (int nt = 0; nt < 2; nt++)
#pragma unroll
            for (int reg = 0; reg < 4; reg++) {
                int query = w * 64 + mt * 16 + q * 4 + reg;
                att[((size_t)b_ * 256 + query) * 192 + h * 32 + nt * 16 + r] =
                    O[mt][nt][reg] * lp[mt][reg];
            }
}

// ---------------------------------------------------------------- K4: out-proj via bf16 MFMA + LN + roll-scatter + residual
__global__ __launch_bounds__(256) void proj_mfma_k(const float* __restrict__ att,
                                                   const short* __restrict__ wpp,
                                                   const float* __restrict__ proj_b,
                                                   const float* __restrict__ x,
                                                   const float* __restrict__ g1,
                                                   const float* __restrict__ b1n,
                                                   float* __restrict__ out) {
    __shared__ float Z[32 * 196];
    __shared__ float ps[32][8];
    __shared__ float pss[32][8];
    __shared__ float mean_s[32], inv_s[32];
    int tid = threadIdx.x, lane = tid & 63, w = tid >> 6;
    int r = lane & 15, q = lane >> 4;
    int b_ = blockIdx.x >> 3, n0 = (blockIdx.x & 7) << 5;

    short8 af[2][6];
#pragma unroll
    for (int m = 0; m < 2; m++) {
        const float* src = att + ((size_t)b_ * 256 + n0 + m * 16 + r) * 192 + q * 8;
#pragma unroll
        for (int kt = 0; kt < 6; kt++) {
            float4 x0 = *(const float4*)(src + kt * 32);
            float4 x1 = *(const float4*)(src + kt * 32 + 4);
            short8 v;
            v[0] = f2bf(x0.x); v[1] = f2bf(x0.y); v[2] = f2bf(x0.z); v[3] = f2bf(x0.w);
            v[4] = f2bf(x1.x); v[5] = f2bf(x1.y); v[6] = f2bf(x1.z); v[7] = f2bf(x1.w);
            af[m][kt] = v;
        }
    }
    for (int ntl = 0; ntl < 3; ntl++) {
        int nt = w * 3 + ntl;
        float bias = proj_b[nt * 16 + r];
        short8 bfr[6];
#pragma unroll
        for (int kt = 0; kt < 6; kt++)
            bfr[kt] = ((const short8*)wpp)[(size_t)(nt * 6 + kt) * 64 + lane];
        f32x4 a0 = {bias, bias, bias, bias};
        f32x4 a1 = {bias, bias, bias, bias};
#pragma unroll
        for (int kt = 0; kt < 6; kt++) {
            a0 = __builtin_amdgcn_mfma_f32_16x16x32_bf16(af[0][kt], bfr[kt], a0, 0, 0, 0);
            a1 = __builtin_amdgcn_mfma_f32_16x16x32_bf16(af[1][kt], bfr[kt], a1, 0, 0, 0);
        }
        int col = nt * 16 + r;
#pragma unroll
        for (int reg = 0; reg < 4; reg++) {
            Z[(q * 4 + reg) * 196 + col] = a0[reg];
            Z[(16 + q * 4 + reg) * 196 + col] = a1[reg];
        }
    }
    __syncthreads();
    {
        int token = tid >> 3, part = tid & 7;
        float s = 0.f, ss = 0.f;
        const float* zr = &Z[token * 196 + part * 24];
#pragma unroll
        for (int c = 0; c < 24; c++) { float v = zr[c]; s += v; ss += v * v; }
        ps[token][part] = s; pss[token][part] = ss;
    }
    __syncthreads();
    if (tid < 32) {
        float s = 0.f, ss = 0.f;
#pragma unroll
        for (int p = 0; p < 8; p++) { s += ps[tid][p]; ss += pss[tid][p]; }
        float mean = s * (1.0f / 192.0f);
        float var = ss * (1.0f / 192.0f) - mean * mean;
        mean_s[tid] = mean;
        inv_s[tid] = 1.0f / sqrtf(var + 1e-5f);
    }
    __syncthreads();
    int b = b_ >> 7, win = b_ & 127;
    int wt = win >> 6, wh = (win >> 3) & 7, ww = win & 7;
    for (int idx = tid; idx < 6144; idx += 256) {
        int token = idx / 192;
        int ch = idx - token * 192;
        int n = n0 + token;
        int t0 = ((wt * 4 + (n >> 6)) + 2) & 7;
        int h0 = ((wh * 8 + ((n >> 3) & 7)) + 4) & 63;
        int w0 = ((ww * 8 + (n & 7)) + 4) & 63;
        size_t gb = ((size_t)((b * 8 + t0) * 64 + h0) * 64 + w0) * 192;
        float v = (Z[token * 196 + ch] - mean_s[token]) * inv_s[token] * g1[ch] + b1n[ch];
        out[gb + ch] = x[gb + ch] + v;
    }
}

// ---------------------------------------------------------------- K5: MLP via bf16 MFMA, fused fc1+GELU+fc2+LN+residual
#define HSTR 776
__global__ __launch_bounds__(256) void mlp_mfma_k(const short* __restrict__ w1p,
                                                  const short* __restrict__ w2p,
                                                  const float* __restrict__ fc1_b,
                                                  const float* __restrict__ fc2_b,
                                                  const float* __restrict__ g2,
                                                  const float* __restrict__ b2,
                                                  float* __restrict__ out) {
    __shared__ short Hs[32 * HSTR];
    __shared__ float ps[32][8];
    __shared__ float pss[32][8];
    __shared__ float mean_s[32], inv_s[32];
    int tid = threadIdx.x;
    int lane = tid & 63, w = tid >> 6;
    int r = lane & 15, q = lane >> 4;
    size_t tok0 = (size_t)blockIdx.x * 32;

    short8 af[2][6];
#pragma unroll
    for (int m = 0; m < 2; m++)
#pragma unroll
        for (int kt = 0; kt < 6; kt++) {
            const float* src = out + (tok0 + m * 16 + r) * 192 + kt * 32 + q * 8;
            float4 x0 = *(const float4*)src;
            float4 x1 = *(const float4*)(src + 4);
            short8 v;
            v[0] = f2bf(x0.x); v[1] = f2bf(x0.y); v[2] = f2bf(x0.z); v[3] = f2bf(x0.w);
            v[4] = f2bf(x1.x); v[5] = f2bf(x1.y); v[6] = f2bf(x1.z); v[7] = f2bf(x1.w);
            af[m][kt] = v;
        }

    for (int ntl = 0; ntl < 12; ntl++) {
        int nt = w * 12 + ntl;
        float bias = fc1_b[nt * 16 + r];
        short8 bfr[6];
#pragma unroll
        for (int kt = 0; kt < 6; kt++)
            bfr[kt] = ((const short8*)w1p)[(size_t)(nt * 6 + kt) * 64 + lane];
        f32x4 acc0 = {bias, bias, bias, bias};
        f32x4 acc1 = {bias, bias, bias, bias};
#pragma unroll
        for (int kt = 0; kt < 6; kt++) {
            acc0 = __builtin_amdgcn_mfma_f32_16x16x32_bf16(af[0][kt], bfr[kt], acc0, 0, 0, 0);
            acc1 = __builtin_amdgcn_mfma_f32_16x16x32_bf16(af[1][kt], bfr[kt], acc1, 0, 0, 0);
        }
        int col = nt * 16 + r;
#pragma unroll
        for (int reg = 0; reg < 4; reg++) {
            float u0 = acc0[reg];
            float u1 = acc1[reg];
            float gl0 = 0.5f * u0 * (1.0f + erff(u0 * 0.70710678118654752f));
            float gl1 = 0.5f * u1 * (1.0f + erff(u1 * 0.70710678118654752f));
            Hs[(q * 4 + reg) * HSTR + col] = f2bf(gl0);
            Hs[(16 + q * 4 + reg) * HSTR + col] = f2bf(gl1);
        }
    }
    __syncthreads();

    f32x4 acc2[2][3];
#pragma unroll
    for (int m = 0; m < 2; m++)
#pragma unroll
        for (int n = 0; n < 3; n++) acc2[m][n] = (f32x4){0.f, 0.f, 0.f, 0.f};
    for (int kk = 0; kk < 24; kk++) {
        short8 a0 = *(const short8*)&Hs[(r) * HSTR + kk * 32 + q * 8];
        short8 a1 = *(const short8*)&Hs[(16 + r) * HSTR + kk * 32 + q * 8];
#pragma unroll
        for (int n = 0; n < 3; n++) {
            int nt = w * 3 + n;
            short8 bfr = ((const short8*)w2p)[(size_t)(nt * 24 + kk) * 64 + lane];
            acc2[0][n] = __builtin_amdgcn_mfma_f32_16x16x32_bf16(a0, bfr, acc2[0][n], 0, 0, 0);
            acc2[1][n] = __builtin_amdgcn_mfma_f32_16x16x32_bf16(a1, bfr, acc2[1][n], 0, 0, 0);
        }
    }
    __syncthreads();
    float* Z = (float*)Hs;
#pragma unroll
    for (int m = 0; m < 2; m++)
#pragma unroll
        for (int n = 0; n < 3; n++) {
            int nt = w * 3 + n;
            int col = nt * 16 + r;
            float bias2 = fc2_b[col];
#pragma unroll
            for (int reg = 0; reg < 4; reg++)
                Z[(m * 16 + q * 4 + reg) * 193 + col] = acc2[m][n][reg] + bias2;
        }
    __syncthreads();

    {
        int token = tid >> 3, part = tid & 7;
        float s = 0.f, ss = 0.f;
        const float* zr = &Z[token * 193 + part * 24];
#pragma unroll
        for (int c = 0; c < 24; c++) { float v = zr[c]; s += v; ss += v * v; }
        ps[token][part] = s; pss[token][part] = ss;
    }
    __syncthreads();
    if (tid < 32) {
        float s = 0.f, ss = 0.f;
#pragma unroll
        for (int p = 0; p < 8; p++) { s += ps[tid][p]; ss += pss[tid][p]; }
        float mean = s * (1.0f / 192.0f);
        float var = ss * (1.0f / 192.0f) - mean * mean;
        mean_s[tid] = mean;
        inv_s[tid] = 1.0f / sqrtf(var + 1e-5f);
    }
    __syncthreads();
    for (int rep = 0; rep < 24; rep++) {
        int idx = rep * 256 + tid;
        int token = idx / 192;
        int ch = idx - token * 192;
        float v = (Z[token * 193 + ch] - mean_s[token]) * inv_s[token] * g2[ch] + b2[ch];
        size_t gi = (tok0 + token) * 192 + ch;
        out[gi] = out[gi] + v;
    }
}

// ---------------------------------------------------------------- launch
extern "C" void kernel_launch(void* const* d_in, const int* in_sizes, int n_in,
                              void* d_out, int out_size, void* d_ws, size_t ws_size,
                              hipStream_t stream) {
    const float* x           = (const float*)d_in[0];
    const float* qkv_w       = (const float*)d_in[1];
    const float* qkv_b       = (const float*)d_in[2];
    const float* proj_w      = (const float*)d_in[3];
    const float* proj_b      = (const float*)d_in[4];
    const float* cpb_w1      = (const float*)d_in[5];
    const float* cpb_b1      = (const float*)d_in[6];
    const float* cpb_w2      = (const float*)d_in[7];
    const float* logit_scale = (const float*)d_in[8];
    const float* norm1_g     = (const float*)d_in[9];
    const float* norm1_b     = (const float*)d_in[10];
    const float* norm2_g     = (const float*)d_in[11];
    const float* norm2_b     = (const float*)d_in[12];
    const float* fc1_w       = (const float*)d_in[13];
    const float* fc1_b       = (const float*)d_in[14];
    const float* fc2_w       = (const float*)d_in[15];
    const float* fc2_b       = (const float*)d_in[16];
    float* out = (float*)d_out;

    float* ws = (float*)d_ws;
    const size_t QKVE = (size_t)256 * 6 * 256 * 32;   // 12,582,912 elems
    float* att    = ws;                               // fp32
    float* biasT  = att + QKVE + ((size_t)256 * 256 * 192 - QKVE);  // = att + 12,582,912
    // (att is 256*256*192 = 12,582,912 floats — same count as QKVE)
    float* tbl6   = biasT + (size_t)6 * 256 * 256;    // 393,216 floats
    short* w1pack = (short*)(tbl6 + 9472);
    short* w2pack = w1pack + (size_t)768 * 192;
    short* wqpack = w2pack + (size_t)192 * 768;
    short* wppack = wqpack + (size_t)576 * 192;
    short* qbf    = wppack + (size_t)192 * 192;       // bf16, 12,582,912 each
    short* kbf    = qbf + QKVE;
    short* vtb    = kbf + QKVE;

    hipLaunchKernelGGL(pack_w_k, dim3(288), dim3(64), 0, stream, fc1_w, w1pack, 192);
    hipLaunchKernelGGL(pack_w_k, dim3(288), dim3(64), 0, stream, fc2_w, w2pack, 768);
    hipLaunchKernelGGL(pack_w_k, dim3(216), dim3(64), 0, stream, qkv_w, wqpack, 192);
    hipLaunchKernelGGL(pack_w_k, dim3(72), dim3(64), 0, stream, proj_w, wppack, 192);
    hipLaunchKernelGGL(cpb_table_k, dim3(1575), dim3(512), 0, stream, cpb_w1, cpb_b1, cpb_w2, tbl6);
    hipLaunchKernelGGL(bias_k, dim3(1536), dim3(256), 0, stream, tbl6, biasT);
    hipLaunchKernelGGL(qkv_mfma_k, dim3(2048), dim3(256), 0, stream, x, wqpack, qkv_b, qbf, kbf, vtb);
    hipLaunchKernelGGL(attn_mfma_k, dim3(1536), dim3(256), 0, stream, qbf, kbf, vtb, biasT, logit_scale, att);
    hipLaunchKernelGGL(proj_mfma_k, dim3(2048), dim3(256), 0, stream, att, wppack, proj_b, x, norm1_g, norm1_b, out);
    hipLaunchKernelGGL(mlp_mfma_k, dim3(2048), dim3(256), 0, stream, w1pack, w2pack,
                       fc1_b, fc2_b, norm2_g, norm2_b, out);
}

// Round 5
// 430.914 us; speedup vs baseline: 6.8807x; 1.0224x over previous
//
#include <hip/hip_runtime.h>
#include <math.h>

// Problem constants
// B=2, T=8, H=64, W=64, C=192, WIN=(4,8,8), SHIFT=(2,4,4), HEADS=6, d=32
// N=256 tokens/window, nW=128 windows/batch, B_=256 windows total, HID=768

typedef short short8 __attribute__((ext_vector_type(8)));
typedef short short4v __attribute__((ext_vector_type(4)));
typedef float f32x4 __attribute__((ext_vector_type(4)));

__device__ __forceinline__ short f2bf(float f) {
    union { float f; unsigned u; } v; v.f = f;
    unsigned r = v.u + 0x7FFF + ((v.u >> 16) & 1);  // RNE
    return (short)(r >> 16);
}

// tanh-form GELU reduced to sigmoid: x * sigmoid(1.5957691*x*(1+0.044715*x^2))
__device__ __forceinline__ float gelu_fast(float x) {
    float s = x * x;
    float t = fmaf(0.044715f, s, 1.0f);
    float y = -1.5957691216057308f * x * t;
    return x / (1.0f + __expf(y));
}

// ---------------------------------------------------------------- K0: pack fp32 weight (Nout, K) -> bf16 B-fragment order
// frag (nt, kt): lane l holds B[k=(l>>4)*8+j][n=l&15] = W[nt*16+(l&15)][kt*32+(l>>4)*8+j]
__global__ __launch_bounds__(64) void pack_w_k(const float* __restrict__ w,
                                               short* __restrict__ dst, int K) {
    int lane = threadIdx.x;
    int ktn = K >> 5;
    int nt = blockIdx.x / ktn, kt = blockIdx.x % ktn;
    int r = lane & 15, q = lane >> 4;
    const float* src = w + (size_t)(nt * 16 + r) * K + kt * 32 + q * 8;
    short8 v;
#pragma unroll
    for (int j = 0; j < 8; j++) v[j] = f2bf(src[j]);
    ((short8*)dst)[(size_t)blockIdx.x * 64 + lane] = v;
}

// ---------------------------------------------------------------- K1a: CPB MLP table — one wave per m, shuffle reduction
__global__ __launch_bounds__(64) void cpb_table_k(const float* __restrict__ w1,
                                                  const float* __restrict__ b1,
                                                  const float* __restrict__ w2,
                                                  float* __restrict__ tbl6) {
    int m = blockIdx.x;
    int lane = threadIdx.x;
    int it = m / 225;
    int ih = (m / 15) % 15;
    int iw = m % 15;
    float r0 = (float)(it - 3) * (8.0f / 3.0f);
    float r1 = (float)(ih - 7) * (8.0f / 7.0f);
    float r2 = (float)(iw - 7) * (8.0f / 7.0f);
    float c0 = (r0 < 0.f ? -1.f : 1.f) * log2f(fabsf(r0) + 1.0f) * (1.0f / 3.0f);
    float c1 = (r1 < 0.f ? -1.f : 1.f) * log2f(fabsf(r1) + 1.0f) * (1.0f / 3.0f);
    float c2 = (r2 < 0.f ? -1.f : 1.f) * log2f(fabsf(r2) + 1.0f) * (1.0f / 3.0f);
    float hv[8];
#pragma unroll
    for (int j = 0; j < 8; j++) {
        int t = lane * 8 + j;
        hv[j] = fmaxf(0.0f, c0 * w1[3 * t] + c1 * w1[3 * t + 1] + c2 * w1[3 * t + 2] + b1[t]);
    }
#pragma unroll
    for (int head = 0; head < 6; head++) {
        float s = 0.f;
#pragma unroll
        for (int j = 0; j < 8; j++) s += hv[j] * w2[head * 512 + lane * 8 + j];
        s += __shfl_xor(s, 1);
        s += __shfl_xor(s, 2);
        s += __shfl_xor(s, 4);
        s += __shfl_xor(s, 8);
        s += __shfl_xor(s, 16);
        s += __shfl_xor(s, 32);
        if (lane == 0) tbl6[m * 6 + head] = s;
    }
}

// ---------------------------------------------------------------- K1b: biasT[h][key][query] = 16*sigmoid(cpb(query,key))  (TRANSPOSED)
__global__ __launch_bounds__(256) void bias_k(const float* __restrict__ tbl6,
                                              float* __restrict__ biasT) {
    int idx = blockIdx.x * 256 + threadIdx.x;  // h*65536 + key*256 + query
    int h = idx >> 16;
    int rem = idx & 65535;
    int jj = rem >> 8, ii = rem & 255;  // jj = key, ii = query
    int dt = (ii >> 6) - (jj >> 6) + 3;
    int dh = ((ii >> 3) & 7) - ((jj >> 3) & 7) + 7;
    int dw = (ii & 7) - (jj & 7) + 7;
    int rel = dt * 225 + dh * 15 + dw;
    float v = tbl6[rel * 6 + h];
    biasT[idx] = 16.0f / (1.0f + expf(-v));
}

// ---------------------------------------------------------------- K2: QKV via bf16 MFMA + shifted-window gather + q/k normalize
// Outputs: qbf/kbf bf16 [b_,h,256,32] normalized; vtb bf16 [b_,h,32,256] (V transposed).
#define ZSTR 388
__global__ __launch_bounds__(256) void qkv_mfma_k(const float* __restrict__ x,
                                                  const short* __restrict__ wqp,
                                                  const float* __restrict__ qkv_b,
                                                  short* __restrict__ qbf,
                                                  short* __restrict__ kbf,
                                                  short* __restrict__ vtb) {
    __shared__ float Z[32 * ZSTR];  // q,k channels 0..383 (49664 B)
    int tid = threadIdx.x, lane = tid & 63, w = tid >> 6;
    int r = lane & 15, q = lane >> 4;
    int b_ = blockIdx.x >> 3, n0 = (blockIdx.x & 7) << 5;
    int b = b_ >> 7, win = b_ & 127;
    int wt = win >> 6, wh = (win >> 3) & 7, ww = win & 7;

    // A fragments straight from global x with roll-gather
    short8 af[2][6];
#pragma unroll
    for (int m = 0; m < 2; m++) {
        int n = n0 + m * 16 + r;
        int t0 = ((wt * 4 + (n >> 6)) + 2) & 7;
        int h0 = ((wh * 8 + ((n >> 3) & 7)) + 4) & 63;
        int w0 = ((ww * 8 + (n & 7)) + 4) & 63;
        const float* src = x + ((size_t)((b * 8 + t0) * 64 + h0) * 64 + w0) * 192 + q * 8;
#pragma unroll
        for (int kt = 0; kt < 6; kt++) {
            float4 x0 = *(const float4*)(src + kt * 32);
            float4 x1 = *(const float4*)(src + kt * 32 + 4);
            short8 v;
            v[0] = f2bf(x0.x); v[1] = f2bf(x0.y); v[2] = f2bf(x0.z); v[3] = f2bf(x0.w);
            v[4] = f2bf(x1.x); v[5] = f2bf(x1.y); v[6] = f2bf(x1.z); v[7] = f2bf(x1.w);
            af[m][kt] = v;
        }
    }

    for (int ntl = 0; ntl < 9; ntl++) {
        int nt = w * 9 + ntl;
        float bias = qkv_b[nt * 16 + r];
        short8 bfr[6];
#pragma unroll
        for (int kt = 0; kt < 6; kt++)
            bfr[kt] = ((const short8*)wqp)[(size_t)(nt * 6 + kt) * 64 + lane];
        f32x4 a0 = {bias, bias, bias, bias};
        f32x4 a1 = {bias, bias, bias, bias};
#pragma unroll
        for (int kt = 0; kt < 6; kt++) {
            a0 = __builtin_amdgcn_mfma_f32_16x16x32_bf16(af[0][kt], bfr[kt], a0, 0, 0, 0);
            a1 = __builtin_amdgcn_mfma_f32_16x16x32_bf16(af[1][kt], bfr[kt], a1, 0, 0, 0);
        }
        int col = nt * 16 + r;
        if (nt < 24) {  // q,k -> LDS for normalization
#pragma unroll
            for (int reg = 0; reg < 4; reg++) {
                Z[(q * 4 + reg) * ZSTR + col] = a0[reg];
                Z[(16 + q * 4 + reg) * ZSTR + col] = a1[reg];
            }
        } else {  // v -> global transposed bf16: vtb[(b_*6+h)*32+d][key]
            int ch = col - 384;
            int hh = ch >> 5, dd = ch & 31;
            short* vb = vtb + ((size_t)(b_ * 6 + hh) * 32 + dd) * 256 + n0;
            short4v p0, p1;
#pragma unroll
            for (int reg = 0; reg < 4; reg++) { p0[reg] = f2bf(a0[reg]); p1[reg] = f2bf(a1[reg]); }
            *(short4v*)(vb + q * 4) = p0;        // keys n0 + q*4 + reg
            *(short4v*)(vb + 16 + q * 4) = p1;   // keys n0 + 16 + q*4 + reg
        }
    }
    __syncthreads();
    // normalize q/k: 32 tokens x 12 rows (6 q-heads + 6 k-heads), write bf16
    for (int rw = tid; rw < 384; rw += 256) {
        int token = rw / 12, rr = rw - token * 12;
        int isq = rr < 6 ? 1 : 0;
        int h = isq ? rr : rr - 6;
        const float* rp = &Z[token * ZSTR + rr * 32];
        float ss = 0.f;
#pragma unroll
        for (int d = 0; d < 32; d++) ss += rp[d] * rp[d];
        float inv = 1.0f / fmaxf(sqrtf(ss), 1e-12f);
        short* dst = (isq ? qbf : kbf) + ((size_t)(b_ * 6 + h) * 256 + n0 + token) * 32;
#pragma unroll
        for (int d8 = 0; d8 < 4; d8++) {
            short8 v;
#pragma unroll
            for (int j = 0; j < 8; j++) v[j] = f2bf(rp[d8 * 8 + j] * inv);
            *(short8*)(dst + d8 * 8) = v;
        }
    }
}

// ---------------------------------------------------------------- K3: flash attention via bf16 MFMA, one block per (window, head)
#define KSTR 40
#define VSTR 264
#define PSTR 40
__global__ __launch_bounds__(256) void attn_mfma_k(const short* __restrict__ qbf,
                                                   const short* __restrict__ kbf,
                                                   const short* __restrict__ vtb,
                                                   const float* __restrict__ biasT,
                                                   const float* __restrict__ logit_scale,
                                                   float* __restrict__ att) {
    __shared__ short Ks[256 * KSTR];      // 20480 B
    __shared__ short Vs[32 * VSTR];       // 16896 B
    __shared__ short Ps[4][16 * PSTR];    // 5120 B (wave-private P tiles)
    int tid = threadIdx.x, lane = tid & 63, w = tid >> 6;
    int r = lane & 15, q = lane >> 4;
    int b_ = blockIdx.x / 6, h = blockIdx.x % 6;
    size_t base = (size_t)(b_ * 6 + h) * 8192;

    const short8* kg = (const short8*)(kbf + base);
    const short8* vg = (const short8*)(vtb + base);
    for (int i = tid; i < 1024; i += 256) {
        short8 kv = kg[i];
        *(short8*)&Ks[(i >> 2) * KSTR + (i & 3) * 8] = kv;
        short8 vv = vg[i];
        *(short8*)&Vs[(i >> 5) * VSTR + (i & 31) * 8] = vv;
    }

    short8 qf[4];
#pragma unroll
    for (int mt = 0; mt < 4; mt++)
        qf[mt] = *(const short8*)(qbf + base + (size_t)(w * 64 + mt * 16 + r) * 32 + q * 8);

    float scale = __expf(fminf(logit_scale[h], 4.6051702f));
    float M = scale + 16.0f;
    int win = b_ & 127;
    int wt4 = (win >> 6) * 4, wh8 = ((win >> 3) & 7) * 8, ww8 = (win & 7) * 8;
    auto region = [&](int n) {
        int ts = wt4 + (n >> 6), hs = wh8 + ((n >> 3) & 7), wsv = ww8 + (n & 7);
        int rt = ts < 4 ? 0 : (ts < 6 ? 1 : 2);
        int rh = hs < 56 ? 0 : (hs < 60 ? 1 : 2);
        int rw = wsv < 56 ? 0 : (wsv < 60 ? 1 : 2);
        return rt * 9 + rh * 3 + rw;
    };
    int rowreg[4][4];
#pragma unroll
    for (int mt = 0; mt < 4; mt++)
#pragma unroll
        for (int reg = 0; reg < 4; reg++)
            rowreg[mt][reg] = region(w * 64 + mt * 16 + q * 4 + reg);

    f32x4 O[4][2];
    float lp[4][4];
#pragma unroll
    for (int mt = 0; mt < 4; mt++) {
        O[mt][0] = (f32x4){0.f, 0.f, 0.f, 0.f};
        O[mt][1] = (f32x4){0.f, 0.f, 0.f, 0.f};
#pragma unroll
        for (int reg = 0; reg < 4; reg++) lp[mt][reg] = 0.f;
    }
    __syncthreads();

    const float* bh = biasT + ((size_t)h << 16);
    for (int s = 0; s < 8; s++) {
        short8 kf0 = *(const short8*)&Ks[(s * 32 + r) * KSTR + q * 8];
        short8 kf1 = *(const short8*)&Ks[(s * 32 + 16 + r) * KSTR + q * 8];
        short8 vf0 = *(const short8*)&Vs[r * VSTR + s * 32 + q * 8];
        short8 vf1 = *(const short8*)&Vs[(16 + r) * VSTR + s * 32 + q * 8];
        int cr0 = region(s * 32 + r);
        int cr1 = region(s * 32 + 16 + r);
#pragma unroll
        for (int mt = 0; mt < 4; mt++) {
            f32x4 s0 = {0.f, 0.f, 0.f, 0.f};
            f32x4 s1 = {0.f, 0.f, 0.f, 0.f};
            s0 = __builtin_amdgcn_mfma_f32_16x16x32_bf16(qf[mt], kf0, s0, 0, 0, 0);
            s1 = __builtin_amdgcn_mfma_f32_16x16x32_bf16(qf[mt], kf1, s1, 0, 0, 0);
            int qcol = w * 64 + mt * 16 + q * 4;
            float4 b0 = *(const float4*)(bh + (size_t)(s * 32 + r) * 256 + qcol);
            float4 b1 = *(const float4*)(bh + (size_t)(s * 32 + 16 + r) * 256 + qcol);
#pragma unroll
            for (int reg = 0; reg < 4; reg++) {
                float bb0 = (reg == 0 ? b0.x : reg == 1 ? b0.y : reg == 2 ? b0.z : b0.w);
                float bb1 = (reg == 0 ? b1.x : reg == 1 ? b1.y : reg == 2 ? b1.z : b1.w);
                float v0 = s0[reg] * scale + bb0 + (cr0 == rowreg[mt][reg] ? 0.f : -100.f) - M;
                float v1 = s1[reg] * scale + bb1 + (cr1 == rowreg[mt][reg] ? 0.f : -100.f) - M;
                float p0 = __expf(v0);
                float p1 = __expf(v1);
                lp[mt][reg] += p0 + p1;
                Ps[w][(q * 4 + reg) * PSTR + r] = f2bf(p0);
                Ps[w][(q * 4 + reg) * PSTR + 16 + r] = f2bf(p1);
            }
            short8 pa = *(const short8*)&Ps[w][r * PSTR + q * 8];
            O[mt][0] = __builtin_amdgcn_mfma_f32_16x16x32_bf16(pa, vf0, O[mt][0], 0, 0, 0);
            O[mt][1] = __builtin_amdgcn_mfma_f32_16x16x32_bf16(pa, vf1, O[mt][1], 0, 0, 0);
        }
    }

#pragma unroll
    for (int mt = 0; mt < 4; mt++)
#pragma unroll
        for (int reg = 0; reg < 4; reg++) {
            float v = lp[mt][reg];
            v += __shfl_xor(v, 1);
            v += __shfl_xor(v, 2);
            v += __shfl_xor(v, 4);
            v += __shfl_xor(v, 8);
            lp[mt][reg] = 1.0f / v;
        }
#pragma unroll
    for (int mt = 0; mt < 4; mt++)
#pragma unroll
        for (int nt = 0; nt < 2; nt++)
#pragma unroll
            for (int reg = 0; reg < 4; reg++) {
                int query = w * 64 + mt * 16 + q * 4 + reg;
                att[((size_t)b_ * 256 + query) * 192 + h * 32 + nt * 16 + r] =
                    O[mt][nt][reg] * lp[mt][reg];
            }
}

// ---------------------------------------------------------------- K4: out-proj via bf16 MFMA + LN + roll-scatter + residual
__global__ __launch_bounds__(256) void proj_mfma_k(const float* __restrict__ att,
                                                   const short* __restrict__ wpp,
                                                   const float* __restrict__ proj_b,
                                                   const float* __restrict__ x,
                                                   const float* __restrict__ g1,
                                                   const float* __restrict__ b1n,
                                                   float* __restrict__ out) {
    __shared__ float Z[32 * 196];
    __shared__ float ps[32][8];
    __shared__ float pss[32][8];
    __shared__ float mean_s[32], inv_s[32];
    int tid = threadIdx.x, lane = tid & 63, w = tid >> 6;
    int r = lane & 15, q = lane >> 4;
    int b_ = blockIdx.x >> 3, n0 = (blockIdx.x & 7) << 5;

    short8 af[2][6];
#pragma unroll
    for (int m = 0; m < 2; m++) {
        const float* src = att + ((size_t)b_ * 256 + n0 + m * 16 + r) * 192 + q * 8;
#pragma unroll
        for (int kt = 0; kt < 6; kt++) {
            float4 x0 = *(const float4*)(src + kt * 32);
            float4 x1 = *(const float4*)(src + kt * 32 + 4);
            short8 v;
            v[0] = f2bf(x0.x); v[1] = f2bf(x0.y); v[2] = f2bf(x0.z); v[3] = f2bf(x0.w);
            v[4] = f2bf(x1.x); v[5] = f2bf(x1.y); v[6] = f2bf(x1.z); v[7] = f2bf(x1.w);
            af[m][kt] = v;
        }
    }
    for (int ntl = 0; ntl < 3; ntl++) {
        int nt = w * 3 + ntl;
        float bias = proj_b[nt * 16 + r];
        short8 bfr[6];
#pragma unroll
        for (int kt = 0; kt < 6; kt++)
            bfr[kt] = ((const short8*)wpp)[(size_t)(nt * 6 + kt) * 64 + lane];
        f32x4 a0 = {bias, bias, bias, bias};
        f32x4 a1 = {bias, bias, bias, bias};
#pragma unroll
        for (int kt = 0; kt < 6; kt++) {
            a0 = __builtin_amdgcn_mfma_f32_16x16x32_bf16(af[0][kt], bfr[kt], a0, 0, 0, 0);
            a1 = __builtin_amdgcn_mfma_f32_16x16x32_bf16(af[1][kt], bfr[kt], a1, 0, 0, 0);
        }
        int col = nt * 16 + r;
#pragma unroll
        for (int reg = 0; reg < 4; reg++) {
            Z[(q * 4 + reg) * 196 + col] = a0[reg];
            Z[(16 + q * 4 + reg) * 196 + col] = a1[reg];
        }
    }
    __syncthreads();
    {
        int token = tid >> 3, part = tid & 7;
        float s = 0.f, ss = 0.f;
        const float* zr = &Z[token * 196 + part * 24];
#pragma unroll
        for (int c = 0; c < 24; c++) { float v = zr[c]; s += v; ss += v * v; }
        ps[token][part] = s; pss[token][part] = ss;
    }
    __syncthreads();
    if (tid < 32) {
        float s = 0.f, ss = 0.f;
#pragma unroll
        for (int p = 0; p < 8; p++) { s += ps[tid][p]; ss += pss[tid][p]; }
        float mean = s * (1.0f / 192.0f);
        float var = ss * (1.0f / 192.0f) - mean * mean;
        mean_s[tid] = mean;
        inv_s[tid] = 1.0f / sqrtf(var + 1e-5f);
    }
    __syncthreads();
    int b = b_ >> 7, win = b_ & 127;
    int wt = win >> 6, wh = (win >> 3) & 7, ww = win & 7;
    for (int idx = tid; idx < 6144; idx += 256) {
        int token = idx / 192;
        int ch = idx - token * 192;
        int n = n0 + token;
        int t0 = ((wt * 4 + (n >> 6)) + 2) & 7;
        int h0 = ((wh * 8 + ((n >> 3) & 7)) + 4) & 63;
        int w0 = ((ww * 8 + (n & 7)) + 4) & 63;
        size_t gb = ((size_t)((b * 8 + t0) * 64 + h0) * 64 + w0) * 192;
        float v = (Z[token * 196 + ch] - mean_s[token]) * inv_s[token] * g1[ch] + b1n[ch];
        out[gb + ch] = x[gb + ch] + v;
    }
}

// ---------------------------------------------------------------- K5: MLP via bf16 MFMA, 512 threads / 32 tokens
// Phase 1: 8 waves x 6 n-tiles of H = gelu(X W1^T + b1) -> LDS bf16
// Phase 2: 24 (nt,m) tasks, 3 per wave (wave-uniform parity split)
#define HSTR 776
__global__ __launch_bounds__(512) void mlp_mfma_k(const short* __restrict__ w1p,
                                                  const short* __restrict__ w2p,
                                                  const float* __restrict__ fc1_b,
                                                  const float* __restrict__ fc2_b,
                                                  const float* __restrict__ g2,
                                                  const float* __restrict__ b2,
                                                  float* __restrict__ out) {
    __shared__ short Hs[32 * HSTR];      // 49664 B; reused as Z fp32 [32][193]
    __shared__ float ps[32][16];
    __shared__ float pss[32][16];
    __shared__ float mean_s[32], inv_s[32];
    int tid = threadIdx.x;
    int lane = tid & 63, w = tid >> 6;   // w in 0..7
    int r = lane & 15, q = lane >> 4;
    size_t tok0 = (size_t)blockIdx.x * 32;

    short8 af[2][6];
#pragma unroll
    for (int m = 0; m < 2; m++)
#pragma unroll
        for (int kt = 0; kt < 6; kt++) {
            const float* src = out + (tok0 + m * 16 + r) * 192 + kt * 32 + q * 8;
            float4 x0 = *(const float4*)src;
            float4 x1 = *(const float4*)(src + 4);
            short8 v;
            v[0] = f2bf(x0.x); v[1] = f2bf(x0.y); v[2] = f2bf(x0.z); v[3] = f2bf(x0.w);
            v[4] = f2bf(x1.x); v[5] = f2bf(x1.y); v[6] = f2bf(x1.z); v[7] = f2bf(x1.w);
            af[m][kt] = v;
        }

    // ---- phase 1: wave w computes n-tiles [w*6, w*6+6)
    for (int ntl = 0; ntl < 6; ntl++) {
        int nt = w * 6 + ntl;
        float bias = fc1_b[nt * 16 + r];
        short8 bfr[6];
#pragma unroll
        for (int kt = 0; kt < 6; kt++)
            bfr[kt] = ((const short8*)w1p)[(size_t)(nt * 6 + kt) * 64 + lane];
        f32x4 acc0 = {bias, bias, bias, bias};
        f32x4 acc1 = {bias, bias, bias, bias};
#pragma unroll
        for (int kt = 0; kt < 6; kt++) {
            acc0 = __builtin_amdgcn_mfma_f32_16x16x32_bf16(af[0][kt], bfr[kt], acc0, 0, 0, 0);
            acc1 = __builtin_amdgcn_mfma_f32_16x16x32_bf16(af[1][kt], bfr[kt], acc1, 0, 0, 0);
        }
        int col = nt * 16 + r;
#pragma unroll
        for (int reg = 0; reg < 4; reg++) {
            Hs[(q * 4 + reg) * HSTR + col] = f2bf(gelu_fast(acc0[reg]));
            Hs[(16 + q * 4 + reg) * HSTR + col] = f2bf(gelu_fast(acc1[reg]));
        }
    }
    __syncthreads();

    // ---- phase 2: tasks t = 3w..3w+2, nt = t>>1, m = t&1 (wave-uniform)
    int odd = w & 1;
    int ntA = (3 * w) >> 1, ntB = ntA + 1;
    f32x4 acc2[3];
#pragma unroll
    for (int i = 0; i < 3; i++) acc2[i] = (f32x4){0.f, 0.f, 0.f, 0.f};
    for (int kk = 0; kk < 24; kk++) {
        short8 a0 = *(const short8*)&Hs[r * HSTR + kk * 32 + q * 8];
        short8 a1 = *(const short8*)&Hs[(16 + r) * HSTR + kk * 32 + q * 8];
        short8 bA = ((const short8*)w2p)[(size_t)(ntA * 24 + kk) * 64 + lane];
        short8 bB = ((const short8*)w2p)[(size_t)(ntB * 24 + kk) * 64 + lane];
        if (!odd) {
            acc2[0] = __builtin_amdgcn_mfma_f32_16x16x32_bf16(a0, bA, acc2[0], 0, 0, 0);
            acc2[1] = __builtin_amdgcn_mfma_f32_16x16x32_bf16(a1, bA, acc2[1], 0, 0, 0);
            acc2[2] = __builtin_amdgcn_mfma_f32_16x16x32_bf16(a0, bB, acc2[2], 0, 0, 0);
        } else {
            acc2[0] = __builtin_amdgcn_mfma_f32_16x16x32_bf16(a1, bA, acc2[0], 0, 0, 0);
            acc2[1] = __builtin_amdgcn_mfma_f32_16x16x32_bf16(a0, bB, acc2[1], 0, 0, 0);
            acc2[2] = __builtin_amdgcn_mfma_f32_16x16x32_bf16(a1, bB, acc2[2], 0, 0, 0);
        }
    }
    __syncthreads();  // all H reads complete before overwriting region with Z
    float* Z = (float*)Hs;  // [32][193]
    {
        int tnts[3], tms[3];
        tnts[0] = ntA; tms[0] = odd;
        tnts[1] = odd ? ntB : ntA; tms[1] = odd ? 0 : 1;
        tnts[2] = ntB; tms[2] = odd;
#pragma unroll
        for (int i = 0; i < 3; i++) {
            int col = tnts[i] * 16 + r;
            float bias2 = fc2_b[col];
#pragma unroll
            for (int reg = 0; reg < 4; reg++)
                Z[(tms[i] * 16 + q * 4 + reg) * 193 + col] = acc2[i][reg] + bias2;
        }
    }
    __syncthreads();

    // ---- LN stats: 16 threads per token, 12 channels each
    {
        int token = tid >> 4, part = tid & 15;
        float s = 0.f, ss = 0.f;
        const float* zr = &Z[token * 193 + part * 12];
#pragma unroll
        for (int c = 0; c < 12; c++) { float v = zr[c]; s += v; ss += v * v; }
        ps[token][part] = s; pss[token][part] = ss;
    }
    __syncthreads();
    if (tid < 32) {
        float s = 0.f, ss = 0.f;
#pragma unroll
        for (int p = 0; p < 16; p++) { s += ps[tid][p]; ss += pss[tid][p]; }
        float mean = s * (1.0f / 192.0f);
        float var = ss * (1.0f / 192.0f) - mean * mean;
        mean_s[tid] = mean;
        inv_s[tid] = 1.0f / sqrtf(var + 1e-5f);
    }
    __syncthreads();
    // ---- epilogue: out = x_mid + LN(Z)*g2 + b2   (6144 elems, 12/thread)
    for (int rep = 0; rep < 12; rep++) {
        int idx = rep * 512 + tid;
        int token = idx / 192;
        int ch = idx - token * 192;
        float v = (Z[token * 193 + ch] - mean_s[token]) * inv_s[token] * g2[ch] + b2[ch];
        size_t gi = (tok0 + token) * 192 + ch;
        out[gi] = out[gi] + v;
    }
}

// ---------------------------------------------------------------- launch
extern "C" void kernel_launch(void* const* d_in, const int* in_sizes, int n_in,
                              void* d_out, int out_size, void* d_ws, size_t ws_size,
                              hipStream_t stream) {
    const float* x           = (const float*)d_in[0];
    const float* qkv_w       = (const float*)d_in[1];
    const float* qkv_b       = (const float*)d_in[2];
    const float* proj_w      = (const float*)d_in[3];
    const float* proj_b      = (const float*)d_in[4];
    const float* cpb_w1      = (const float*)d_in[5];
    const float* cpb_b1      = (const float*)d_in[6];
    const float* cpb_w2      = (const float*)d_in[7];
    const float* logit_scale = (const float*)d_in[8];
    const float* norm1_g     = (const float*)d_in[9];
    const float* norm1_b     = (const float*)d_in[10];
    const float* norm2_g     = (const float*)d_in[11];
    const float* norm2_b     = (const float*)d_in[12];
    const float* fc1_w       = (const float*)d_in[13];
    const float* fc1_b       = (const float*)d_in[14];
    const float* fc2_w       = (const float*)d_in[15];
    const float* fc2_b       = (const float*)d_in[16];
    float* out = (float*)d_out;

    float* ws = (float*)d_ws;
    const size_t QKVE = (size_t)256 * 6 * 256 * 32;   // 12,582,912 elems
    float* att    = ws;                               // fp32, 12,582,912
    float* biasT  = att + QKVE;                       // 393,216 fp32
    float* tbl6   = biasT + (size_t)6 * 256 * 256;    // 9,450 fp32
    short* w1pack = (short*)(tbl6 + 9472);
    short* w2pack = w1pack + (size_t)768 * 192;
    short* wqpack = w2pack + (size_t)192 * 768;
    short* wppack = wqpack + (size_t)576 * 192;
    short* qbf    = wppack + (size_t)192 * 192;       // bf16, 12,582,912 each
    short* kbf    = qbf + QKVE;
    short* vtb    = kbf + QKVE;

    hipLaunchKernelGGL(pack_w_k, dim3(288), dim3(64), 0, stream, fc1_w, w1pack, 192);
    hipLaunchKernelGGL(pack_w_k, dim3(288), dim3(64), 0, stream, fc2_w, w2pack, 768);
    hipLaunchKernelGGL(pack_w_k, dim3(216), dim3(64), 0, stream, qkv_w, wqpack, 192);
    hipLaunchKernelGGL(pack_w_k, dim3(72), dim3(64), 0, stream, proj_w, wppack, 192);
    hipLaunchKernelGGL(cpb_table_k, dim3(1575), dim3(64), 0, stream, cpb_w1, cpb_b1, cpb_w2, tbl6);
    hipLaunchKernelGGL(bias_k, dim3(1536), dim3(256), 0, stream, tbl6, biasT);
    hipLaunchKernelGGL(qkv_mfma_k, dim3(2048), dim3(256), 0, stream, x, wqpack, qkv_b, qbf, kbf, vtb);
    hipLaunchKernelGGL(attn_mfma_k, dim3(1536), dim3(256), 0, stream, qbf, kbf, vtb, biasT, logit_scale, att);
    hipLaunchKernelGGL(proj_mfma_k, dim3(2048), dim3(256), 0, stream, att, wppack, proj_b, x, norm1_g, norm1_b, out);
    hipLaunchKernelGGL(mlp_mfma_k, dim3(2048), dim3(512), 0, stream, w1pack, w2pack,
                       fc1_b, fc2_b, norm2_g, norm2_b, out);
}

// Round 6
// 422.769 us; speedup vs baseline: 7.0133x; 1.0193x over previous
//
#include <hip/hip_runtime.h>
#include <math.h>

// Problem constants
// B=2, T=8, H=64, W=64, C=192, WIN=(4,8,8), SHIFT=(2,4,4), HEADS=6, d=32
// N=256 tokens/window, nW=128 windows/batch, B_=256 windows total, HID=768

typedef short short8 __attribute__((ext_vector_type(8)));
typedef short short4v __attribute__((ext_vector_type(4)));
typedef float f32x4 __attribute__((ext_vector_type(4)));

__device__ __forceinline__ short f2bf(float f) {
    union { float f; unsigned u; } v; v.f = f;
    unsigned r = v.u + 0x7FFF + ((v.u >> 16) & 1);  // RNE
    return (short)(r >> 16);
}

// tanh-form GELU reduced to sigmoid: x * sigmoid(1.5957691*x*(1+0.044715*x^2))
__device__ __forceinline__ float gelu_fast(float x) {
    float s = x * x;
    float t = fmaf(0.044715f, s, 1.0f);
    float y = -1.5957691216057308f * x * t;
    return x / (1.0f + __expf(y));
}

// ---------------------------------------------------------------- K0: pack fp32 weight (Nout, K) -> bf16 fragment order
// frag (nt, kt): lane l holds W[nt*16+(l&15)][kt*32+(l>>4)*8+j]
// Works as B-frag (W^T as B) AND as A-frag (W as A) — layouts are identical.
__global__ __launch_bounds__(64) void pack_w_k(const float* __restrict__ w,
                                               short* __restrict__ dst, int K) {
    int lane = threadIdx.x;
    int ktn = K >> 5;
    int nt = blockIdx.x / ktn, kt = blockIdx.x % ktn;
    int r = lane & 15, q = lane >> 4;
    const float* src = w + (size_t)(nt * 16 + r) * K + kt * 32 + q * 8;
    short8 v;
#pragma unroll
    for (int j = 0; j < 8; j++) v[j] = f2bf(src[j]);
    ((short8*)dst)[(size_t)blockIdx.x * 64 + lane] = v;
}

// ---------------------------------------------------------------- K1a: CPB MLP table — one wave per m, shuffle reduction
__global__ __launch_bounds__(64) void cpb_table_k(const float* __restrict__ w1,
                                                  const float* __restrict__ b1,
                                                  const float* __restrict__ w2,
                                                  float* __restrict__ tbl6) {
    int m = blockIdx.x;
    int lane = threadIdx.x;
    int it = m / 225;
    int ih = (m / 15) % 15;
    int iw = m % 15;
    float r0 = (float)(it - 3) * (8.0f / 3.0f);
    float r1 = (float)(ih - 7) * (8.0f / 7.0f);
    float r2 = (float)(iw - 7) * (8.0f / 7.0f);
    float c0 = (r0 < 0.f ? -1.f : 1.f) * log2f(fabsf(r0) + 1.0f) * (1.0f / 3.0f);
    float c1 = (r1 < 0.f ? -1.f : 1.f) * log2f(fabsf(r1) + 1.0f) * (1.0f / 3.0f);
    float c2 = (r2 < 0.f ? -1.f : 1.f) * log2f(fabsf(r2) + 1.0f) * (1.0f / 3.0f);
    float hv[8];
#pragma unroll
    for (int j = 0; j < 8; j++) {
        int t = lane * 8 + j;
        hv[j] = fmaxf(0.0f, c0 * w1[3 * t] + c1 * w1[3 * t + 1] + c2 * w1[3 * t + 2] + b1[t]);
    }
#pragma unroll
    for (int head = 0; head < 6; head++) {
        float s = 0.f;
#pragma unroll
        for (int j = 0; j < 8; j++) s += hv[j] * w2[head * 512 + lane * 8 + j];
        s += __shfl_xor(s, 1);
        s += __shfl_xor(s, 2);
        s += __shfl_xor(s, 4);
        s += __shfl_xor(s, 8);
        s += __shfl_xor(s, 16);
        s += __shfl_xor(s, 32);
        if (lane == 0) tbl6[m * 6 + head] = s;
    }
}

// ---------------------------------------------------------------- K1b: biasT[h][key][query] = 16*sigmoid(cpb(query,key))  (TRANSPOSED)
__global__ __launch_bounds__(256) void bias_k(const float* __restrict__ tbl6,
                                              float* __restrict__ biasT) {
    int idx = blockIdx.x * 256 + threadIdx.x;  // h*65536 + key*256 + query
    int h = idx >> 16;
    int rem = idx & 65535;
    int jj = rem >> 8, ii = rem & 255;  // jj = key, ii = query
    int dt = (ii >> 6) - (jj >> 6) + 3;
    int dh = ((ii >> 3) & 7) - ((jj >> 3) & 7) + 7;
    int dw = (ii & 7) - (jj & 7) + 7;
    int rel = dt * 225 + dh * 15 + dw;
    float v = tbl6[rel * 6 + h];
    biasT[idx] = 16.0f / (1.0f + expf(-v));
}

// ---------------------------------------------------------------- K2: QKV via bf16 MFMA + shifted-window gather + q/k normalize
#define ZSTR 388
__global__ __launch_bounds__(256) void qkv_mfma_k(const float* __restrict__ x,
                                                  const short* __restrict__ wqp,
                                                  const float* __restrict__ qkv_b,
                                                  short* __restrict__ qbf,
                                                  short* __restrict__ kbf,
                                                  short* __restrict__ vtb) {
    __shared__ float Z[32 * ZSTR];  // q,k channels 0..383 (49664 B)
    int tid = threadIdx.x, lane = tid & 63, w = tid >> 6;
    int r = lane & 15, q = lane >> 4;
    int b_ = blockIdx.x >> 3, n0 = (blockIdx.x & 7) << 5;
    int b = b_ >> 7, win = b_ & 127;
    int wt = win >> 6, wh = (win >> 3) & 7, ww = win & 7;

    short8 af[2][6];
#pragma unroll
    for (int m = 0; m < 2; m++) {
        int n = n0 + m * 16 + r;
        int t0 = ((wt * 4 + (n >> 6)) + 2) & 7;
        int h0 = ((wh * 8 + ((n >> 3) & 7)) + 4) & 63;
        int w0 = ((ww * 8 + (n & 7)) + 4) & 63;
        const float* src = x + ((size_t)((b * 8 + t0) * 64 + h0) * 64 + w0) * 192 + q * 8;
#pragma unroll
        for (int kt = 0; kt < 6; kt++) {
            float4 x0 = *(const float4*)(src + kt * 32);
            float4 x1 = *(const float4*)(src + kt * 32 + 4);
            short8 v;
            v[0] = f2bf(x0.x); v[1] = f2bf(x0.y); v[2] = f2bf(x0.z); v[3] = f2bf(x0.w);
            v[4] = f2bf(x1.x); v[5] = f2bf(x1.y); v[6] = f2bf(x1.z); v[7] = f2bf(x1.w);
            af[m][kt] = v;
        }
    }

    for (int ntl = 0; ntl < 9; ntl++) {
        int nt = w * 9 + ntl;
        float bias = qkv_b[nt * 16 + r];
        short8 bfr[6];
#pragma unroll
        for (int kt = 0; kt < 6; kt++)
            bfr[kt] = ((const short8*)wqp)[(size_t)(nt * 6 + kt) * 64 + lane];
        f32x4 a0 = {bias, bias, bias, bias};
        f32x4 a1 = {bias, bias, bias, bias};
#pragma unroll
        for (int kt = 0; kt < 6; kt++) {
            a0 = __builtin_amdgcn_mfma_f32_16x16x32_bf16(af[0][kt], bfr[kt], a0, 0, 0, 0);
            a1 = __builtin_amdgcn_mfma_f32_16x16x32_bf16(af[1][kt], bfr[kt], a1, 0, 0, 0);
        }
        int col = nt * 16 + r;
        if (nt < 24) {  // q,k -> LDS for normalization
#pragma unroll
            for (int reg = 0; reg < 4; reg++) {
                Z[(q * 4 + reg) * ZSTR + col] = a0[reg];
                Z[(16 + q * 4 + reg) * ZSTR + col] = a1[reg];
            }
        } else {  // v -> global transposed bf16: vtb[(b_*6+h)*32+d][key]
            int ch = col - 384;
            int hh = ch >> 5, dd = ch & 31;
            short* vb = vtb + ((size_t)(b_ * 6 + hh) * 32 + dd) * 256 + n0;
            short4v p0, p1;
#pragma unroll
            for (int reg = 0; reg < 4; reg++) { p0[reg] = f2bf(a0[reg]); p1[reg] = f2bf(a1[reg]); }
            *(short4v*)(vb + q * 4) = p0;
            *(short4v*)(vb + 16 + q * 4) = p1;
        }
    }
    __syncthreads();
    for (int rw = tid; rw < 384; rw += 256) {
        int token = rw / 12, rr = rw - token * 12;
        int isq = rr < 6 ? 1 : 0;
        int h = isq ? rr : rr - 6;
        const float* rp = &Z[token * ZSTR + rr * 32];
        float ss = 0.f;
#pragma unroll
        for (int d = 0; d < 32; d++) ss += rp[d] * rp[d];
        float inv = 1.0f / fmaxf(sqrtf(ss), 1e-12f);
        short* dst = (isq ? qbf : kbf) + ((size_t)(b_ * 6 + h) * 256 + n0 + token) * 32;
#pragma unroll
        for (int d8 = 0; d8 < 4; d8++) {
            short8 v;
#pragma unroll
            for (int j = 0; j < 8; j++) v[j] = f2bf(rp[d8 * 8 + j] * inv);
            *(short8*)(dst + d8 * 8) = v;
        }
    }
}

// ---------------------------------------------------------------- K3: flash attention via bf16 MFMA, one block per (window, head)
#define KSTR 40
#define VSTR 264
#define PSTR 40
__global__ __launch_bounds__(256) void attn_mfma_k(const short* __restrict__ qbf,
                                                   const short* __restrict__ kbf,
                                                   const short* __restrict__ vtb,
                                                   const float* __restrict__ biasT,
                                                   const float* __restrict__ logit_scale,
                                                   float* __restrict__ att) {
    __shared__ short Ks[256 * KSTR];      // 20480 B
    __shared__ short Vs[32 * VSTR];       // 16896 B
    __shared__ short Ps[4][16 * PSTR];    // 5120 B (wave-private P tiles)
    int tid = threadIdx.x, lane = tid & 63, w = tid >> 6;
    int r = lane & 15, q = lane >> 4;
    int b_ = blockIdx.x / 6, h = blockIdx.x % 6;
    size_t base = (size_t)(b_ * 6 + h) * 8192;

    const short8* kg = (const short8*)(kbf + base);
    const short8* vg = (const short8*)(vtb + base);
    for (int i = tid; i < 1024; i += 256) {
        short8 kv = kg[i];
        *(short8*)&Ks[(i >> 2) * KSTR + (i & 3) * 8] = kv;
        short8 vv = vg[i];
        *(short8*)&Vs[(i >> 5) * VSTR + (i & 31) * 8] = vv;
    }

    short8 qf[4];
#pragma unroll
    for (int mt = 0; mt < 4; mt++)
        qf[mt] = *(const short8*)(qbf + base + (size_t)(w * 64 + mt * 16 + r) * 32 + q * 8);

    float scale = __expf(fminf(logit_scale[h], 4.6051702f));
    float M = scale + 16.0f;
    int win = b_ & 127;
    int wt4 = (win >> 6) * 4, wh8 = ((win >> 3) & 7) * 8, ww8 = (win & 7) * 8;
    auto region = [&](int n) {
        int ts = wt4 + (n >> 6), hs = wh8 + ((n >> 3) & 7), wsv = ww8 + (n & 7);
        int rt = ts < 4 ? 0 : (ts < 6 ? 1 : 2);
        int rh = hs < 56 ? 0 : (hs < 60 ? 1 : 2);
        int rw = wsv < 56 ? 0 : (wsv < 60 ? 1 : 2);
        return rt * 9 + rh * 3 + rw;
    };
    int rowreg[4][4];
#pragma unroll
    for (int mt = 0; mt < 4; mt++)
#pragma unroll
        for (int reg = 0; reg < 4; reg++)
            rowreg[mt][reg] = region(w * 64 + mt * 16 + q * 4 + reg);

    f32x4 O[4][2];
    float lp[4][4];
#pragma unroll
    for (int mt = 0; mt < 4; mt++) {
        O[mt][0] = (f32x4){0.f, 0.f, 0.f, 0.f};
        O[mt][1] = (f32x4){0.f, 0.f, 0.f, 0.f};
#pragma unroll
        for (int reg = 0; reg < 4; reg++) lp[mt][reg] = 0.f;
    }
    __syncthreads();

    const float* bh = biasT + ((size_t)h << 16);
    for (int s = 0; s < 8; s++) {
        short8 kf0 = *(const short8*)&Ks[(s * 32 + r) * KSTR + q * 8];
        short8 kf1 = *(const short8*)&Ks[(s * 32 + 16 + r) * KSTR + q * 8];
        short8 vf0 = *(const short8*)&Vs[r * VSTR + s * 32 + q * 8];
        short8 vf1 = *(const short8*)&Vs[(16 + r) * VSTR + s * 32 + q * 8];
        int cr0 = region(s * 32 + r);
        int cr1 = region(s * 32 + 16 + r);
#pragma unroll
        for (int mt = 0; mt < 4; mt++) {
            f32x4 s0 = {0.f, 0.f, 0.f, 0.f};
            f32x4 s1 = {0.f, 0.f, 0.f, 0.f};
            s0 = __builtin_amdgcn_mfma_f32_16x16x32_bf16(qf[mt], kf0, s0, 0, 0, 0);
            s1 = __builtin_amdgcn_mfma_f32_16x16x32_bf16(qf[mt], kf1, s1, 0, 0, 0);
            int qcol = w * 64 + mt * 16 + q * 4;
            float4 b0 = *(const float4*)(bh + (size_t)(s * 32 + r) * 256 + qcol);
            float4 b1 = *(const float4*)(bh + (size_t)(s * 32 + 16 + r) * 256 + qcol);
#pragma unroll
            for (int reg = 0; reg < 4; reg++) {
                float bb0 = (reg == 0 ? b0.x : reg == 1 ? b0.y : reg == 2 ? b0.z : b0.w);
                float bb1 = (reg == 0 ? b1.x : reg == 1 ? b1.y : reg == 2 ? b1.z : b1.w);
                float v0 = s0[reg] * scale + bb0 + (cr0 == rowreg[mt][reg] ? 0.f : -100.f) - M;
                float v1 = s1[reg] * scale + bb1 + (cr1 == rowreg[mt][reg] ? 0.f : -100.f) - M;
                float p0 = __expf(v0);
                float p1 = __expf(v1);
                lp[mt][reg] += p0 + p1;
                Ps[w][(q * 4 + reg) * PSTR + r] = f2bf(p0);
                Ps[w][(q * 4 + reg) * PSTR + 16 + r] = f2bf(p1);
            }
            short8 pa = *(const short8*)&Ps[w][r * PSTR + q * 8];
            O[mt][0] = __builtin_amdgcn_mfma_f32_16x16x32_bf16(pa, vf0, O[mt][0], 0, 0, 0);
            O[mt][1] = __builtin_amdgcn_mfma_f32_16x16x32_bf16(pa, vf1, O[mt][1], 0, 0, 0);
        }
    }

#pragma unroll
    for (int mt = 0; mt < 4; mt++)
#pragma unroll
        for (int reg = 0; reg < 4; reg++) {
            float v = lp[mt][reg];
            v += __shfl_xor(v, 1);
            v += __shfl_xor(v, 2);
            v += __shfl_xor(v, 4);
            v += __shfl_xor(v, 8);
            lp[mt][reg] = 1.0f / v;
        }
#pragma unroll
    for (int mt = 0; mt < 4; mt++)
#pragma unroll
        for (int nt = 0; nt < 2; nt++)
#pragma unroll
            for (int reg = 0; reg < 4; reg++) {
                int query = w * 64 + mt * 16 + q * 4 + reg;
                att[((size_t)b_ * 256 + query) * 192 + h * 32 + nt * 16 + r] =
                    O[mt][nt][reg] * lp[mt][reg];
            }
}

// ---------------------------------------------------------------- K4: out-proj via bf16 MFMA (swapped operands) + LN + roll-scatter + residual
// Also emits xmb: bf16 copy of x_mid in raster order for the MLP kernel.
__global__ __launch_bounds__(256) void proj_mfma_k(const float* __restrict__ att,
                                                   const short* __restrict__ wpp,
                                                   const float* __restrict__ proj_b,
                                                   const float* __restrict__ x,
                                                   const float* __restrict__ g1,
                                                   const float* __restrict__ b1n,
                                                   float* __restrict__ out,
                                                   short* __restrict__ xmb) {
    __shared__ float Z[32 * 196];
    __shared__ float ps[32][8];
    __shared__ float pss[32][8];
    __shared__ float mean_s[32], inv_s[32];
    int tid = threadIdx.x, lane = tid & 63, w = tid >> 6;
    int r = lane & 15, q = lane >> 4;
    int b_ = blockIdx.x >> 3, n0 = (blockIdx.x & 7) << 5;

    short8 af[2][6];
#pragma unroll
    for (int m = 0; m < 2; m++) {
        const float* src = att + ((size_t)b_ * 256 + n0 + m * 16 + r) * 192 + q * 8;
#pragma unroll
        for (int kt = 0; kt < 6; kt++) {
            float4 x0 = *(const float4*)(src + kt * 32);
            float4 x1 = *(const float4*)(src + kt * 32 + 4);
            short8 v;
            v[0] = f2bf(x0.x); v[1] = f2bf(x0.y); v[2] = f2bf(x0.z); v[3] = f2bf(x0.w);
            v[4] = f2bf(x1.x); v[5] = f2bf(x1.y); v[6] = f2bf(x1.z); v[7] = f2bf(x1.w);
            af[m][kt] = v;
        }
    }
    for (int ntl = 0; ntl < 3; ntl++) {
        int nt = w * 3 + ntl;
        f32x4 binit = *(const f32x4*)(proj_b + nt * 16 + q * 4);
        short8 bfr[6];
#pragma unroll
        for (int kt = 0; kt < 6; kt++)
            bfr[kt] = ((const short8*)wpp)[(size_t)(nt * 6 + kt) * 64 + lane];
        f32x4 a0 = binit, a1 = binit;
#pragma unroll
        for (int kt = 0; kt < 6; kt++) {
            // swapped: A = weight frag, B = token frag -> C/D col = token, rows = channels
            a0 = __builtin_amdgcn_mfma_f32_16x16x32_bf16(bfr[kt], af[0][kt], a0, 0, 0, 0);
            a1 = __builtin_amdgcn_mfma_f32_16x16x32_bf16(bfr[kt], af[1][kt], a1, 0, 0, 0);
        }
        *(f32x4*)&Z[(r) * 196 + nt * 16 + q * 4] = a0;
        *(f32x4*)&Z[(16 + r) * 196 + nt * 16 + q * 4] = a1;
    }
    __syncthreads();
    {
        int token = tid >> 3, part = tid & 7;
        float s = 0.f, ss = 0.f;
        const float* zr = &Z[token * 196 + part * 24];
#pragma unroll
        for (int c = 0; c < 24; c++) { float v = zr[c]; s += v; ss += v * v; }
        ps[token][part] = s; pss[token][part] = ss;
    }
    __syncthreads();
    if (tid < 32) {
        float s = 0.f, ss = 0.f;
#pragma unroll
        for (int p = 0; p < 8; p++) { s += ps[tid][p]; ss += pss[tid][p]; }
        float mean = s * (1.0f / 192.0f);
        float var = ss * (1.0f / 192.0f) - mean * mean;
        mean_s[tid] = mean;
        inv_s[tid] = 1.0f / sqrtf(var + 1e-5f);
    }
    __syncthreads();
    int b = b_ >> 7, win = b_ & 127;
    int wt = win >> 6, wh = (win >> 3) & 7, ww = win & 7;
    for (int idx = tid; idx < 6144; idx += 256) {
        int token = idx / 192;
        int ch = idx - token * 192;
        int n = n0 + token;
        int t0 = ((wt * 4 + (n >> 6)) + 2) & 7;
        int h0 = ((wh * 8 + ((n >> 3) & 7)) + 4) & 63;
        int w0 = ((ww * 8 + (n & 7)) + 4) & 63;
        size_t gb = ((size_t)((b * 8 + t0) * 64 + h0) * 64 + w0) * 192;
        float v = (Z[token * 196 + ch] - mean_s[token]) * inv_s[token] * g1[ch] + b1n[ch];
        float o = x[gb + ch] + v;
        out[gb + ch] = o;
        xmb[gb + ch] = f2bf(o);
    }
}

// ---------------------------------------------------------------- K5: MLP via bf16 MFMA (swapped operands, prefetched), 512 thr / 32 tokens
#define HSTR 776
__global__ __launch_bounds__(512, 4) void mlp_mfma_k(const short* __restrict__ xmb,
                                                     const short* __restrict__ w1p,
                                                     const short* __restrict__ w2p,
                                                     const float* __restrict__ fc1_b,
                                                     const float* __restrict__ fc2_b,
                                                     const float* __restrict__ g2,
                                                     const float* __restrict__ b2,
                                                     float* __restrict__ out) {
    __shared__ short Hs[32 * HSTR];      // 49664 B; reused as Z fp32 [32][196]
    __shared__ float ps[32][16];
    __shared__ float pss[32][16];
    __shared__ float mean_s[32], inv_s[32];
    int tid = threadIdx.x;
    int lane = tid & 63, w = tid >> 6;   // w in 0..7
    int r = lane & 15, q = lane >> 4;
    size_t tok0 = (size_t)blockIdx.x * 32;

    // A(token) fragments: single 16B bf16 loads (no conversion)
    short8 af[2][6];
#pragma unroll
    for (int m = 0; m < 2; m++)
#pragma unroll
        for (int kt = 0; kt < 6; kt++)
            af[m][kt] = *(const short8*)(xmb + (tok0 + m * 16 + r) * 192 + kt * 32 + q * 8);

    // ---- phase 1: wave w computes hid tiles [w*6, w*6+6); swapped operands:
    // D = mfma(A=W1 frag, B=token frag) -> lane holds H[token=r][hid=nt*16+q*4+reg]
    {
        short8 bw[2][6];
        int nt0 = w * 6;
#pragma unroll
        for (int kt = 0; kt < 6; kt++)
            bw[0][kt] = ((const short8*)w1p)[(size_t)(nt0 * 6 + kt) * 64 + lane];
        for (int ntl = 0; ntl < 6; ntl++) {
            int nt = nt0 + ntl;
            int cur = ntl & 1, nxt = cur ^ 1;
            int ntn = (ntl < 5) ? nt + 1 : nt;   // prefetch next tile's weights
#pragma unroll
            for (int kt = 0; kt < 6; kt++)
                bw[nxt][kt] = ((const short8*)w1p)[(size_t)(ntn * 6 + kt) * 64 + lane];
            f32x4 binit = *(const f32x4*)(fc1_b + nt * 16 + q * 4);
            f32x4 acc0 = binit, acc1 = binit;
#pragma unroll
            for (int kt = 0; kt < 6; kt++) {
                acc0 = __builtin_amdgcn_mfma_f32_16x16x32_bf16(bw[cur][kt], af[0][kt], acc0, 0, 0, 0);
                acc1 = __builtin_amdgcn_mfma_f32_16x16x32_bf16(bw[cur][kt], af[1][kt], acc1, 0, 0, 0);
            }
            short4v p0, p1;
#pragma unroll
            for (int reg = 0; reg < 4; reg++) {
                p0[reg] = f2bf(gelu_fast(acc0[reg]));
                p1[reg] = f2bf(gelu_fast(acc1[reg]));
            }
            *(short4v*)&Hs[(r) * HSTR + nt * 16 + q * 4] = p0;       // 8B vector LDS write
            *(short4v*)&Hs[(16 + r) * HSTR + nt * 16 + q * 4] = p1;
        }
    }
    __syncthreads();

    // ---- phase 2: tasks t = 3w..3w+2, nt = t>>1, m = t&1 (wave-uniform)
    int odd = w & 1;
    int ntA = (3 * w) >> 1, ntB = ntA + 1;
    f32x4 acc2[3];
#pragma unroll
    for (int i = 0; i < 3; i++) acc2[i] = (f32x4){0.f, 0.f, 0.f, 0.f};
    {
        short8 bA = ((const short8*)w2p)[(size_t)(ntA * 24 + 0) * 64 + lane];
        short8 bB = ((const short8*)w2p)[(size_t)(ntB * 24 + 0) * 64 + lane];
        for (int kk = 0; kk < 24; kk++) {
            int kn = (kk < 23) ? kk + 1 : kk;    // prefetch next k-step's weights
            short8 bAn = ((const short8*)w2p)[(size_t)(ntA * 24 + kn) * 64 + lane];
            short8 bBn = ((const short8*)w2p)[(size_t)(ntB * 24 + kn) * 64 + lane];
            short8 a0 = *(const short8*)&Hs[r * HSTR + kk * 32 + q * 8];
            short8 a1 = *(const short8*)&Hs[(16 + r) * HSTR + kk * 32 + q * 8];
            if (!odd) {
                acc2[0] = __builtin_amdgcn_mfma_f32_16x16x32_bf16(bA, a0, acc2[0], 0, 0, 0);
                acc2[1] = __builtin_amdgcn_mfma_f32_16x16x32_bf16(bA, a1, acc2[1], 0, 0, 0);
                acc2[2] = __builtin_amdgcn_mfma_f32_16x16x32_bf16(bB, a0, acc2[2], 0, 0, 0);
            } else {
                acc2[0] = __builtin_amdgcn_mfma_f32_16x16x32_bf16(bA, a1, acc2[0], 0, 0, 0);
                acc2[1] = __builtin_amdgcn_mfma_f32_16x16x32_bf16(bB, a0, acc2[1], 0, 0, 0);
                acc2[2] = __builtin_amdgcn_mfma_f32_16x16x32_bf16(bB, a1, acc2[2], 0, 0, 0);
            }
            bA = bAn; bB = bBn;
        }
    }
    __syncthreads();  // all H reads complete before overwriting region with Z
    float* Z = (float*)Hs;  // [32][196]
    {
        int tnts[3], tms[3];
        tnts[0] = ntA; tms[0] = odd;
        tnts[1] = odd ? ntB : ntA; tms[1] = odd ? 0 : 1;
        tnts[2] = ntB; tms[2] = odd;
#pragma unroll
        for (int i = 0; i < 3; i++) {
            f32x4 b4 = *(const f32x4*)(fc2_b + tnts[i] * 16 + q * 4);
            f32x4 zv = acc2[i] + b4;
            *(f32x4*)&Z[(tms[i] * 16 + r) * 196 + tnts[i] * 16 + q * 4] = zv;  // 16B vector LDS write
        }
    }
    __syncthreads();

    // ---- LN stats: 16 threads per token, 12 channels each
    {
        int token = tid >> 4, part = tid & 15;
        float s = 0.f, ss = 0.f;
        const float* zr = &Z[token * 196 + part * 12];
#pragma unroll
        for (int c = 0; c < 12; c++) { float v = zr[c]; s += v; ss += v * v; }
        ps[token][part] = s; pss[token][part] = ss;
    }
    __syncthreads();
    if (tid < 32) {
        float s = 0.f, ss = 0.f;
#pragma unroll
        for (int p = 0; p < 16; p++) { s += ps[tid][p]; ss += pss[tid][p]; }
        float mean = s * (1.0f / 192.0f);
        float var = ss * (1.0f / 192.0f) - mean * mean;
        mean_s[tid] = mean;
        inv_s[tid] = 1.0f / sqrtf(var + 1e-5f);
    }
    __syncthreads();
    // ---- epilogue: out = x_mid + LN(Z)*g2 + b2   (6144 elems, 12/thread)
    for (int rep = 0; rep < 12; rep++) {
        int idx = rep * 512 + tid;
        int token = idx / 192;
        int ch = idx - token * 192;
        float v = (Z[token * 196 + ch] - mean_s[token]) * inv_s[token] * g2[ch] + b2[ch];
        size_t gi = (tok0 + token) * 192 + ch;
        out[gi] = out[gi] + v;
    }
}

// ---------------------------------------------------------------- launch
extern "C" void kernel_launch(void* const* d_in, const int* in_sizes, int n_in,
                              void* d_out, int out_size, void* d_ws, size_t ws_size,
                              hipStream_t stream) {
    const float* x           = (const float*)d_in[0];
    const float* qkv_w       = (const float*)d_in[1];
    const float* qkv_b       = (const float*)d_in[2];
    const float* proj_w      = (const float*)d_in[3];
    const float* proj_b      = (const float*)d_in[4];
    const float* cpb_w1      = (const float*)d_in[5];
    const float* cpb_b1      = (const float*)d_in[6];
    const float* cpb_w2      = (const float*)d_in[7];
    const float* logit_scale = (const float*)d_in[8];
    const float* norm1_g     = (const float*)d_in[9];
    const float* norm1_b     = (const float*)d_in[10];
    const float* norm2_g     = (const float*)d_in[11];
    const float* norm2_b     = (const float*)d_in[12];
    const float* fc1_w       = (const float*)d_in[13];
    const float* fc1_b       = (const float*)d_in[14];
    const float* fc2_w       = (const float*)d_in[15];
    const float* fc2_b       = (const float*)d_in[16];
    float* out = (float*)d_out;

    float* ws = (float*)d_ws;
    const size_t QKVE = (size_t)256 * 6 * 256 * 32;   // 12,582,912 elems
    float* att    = ws;                               // fp32, 12,582,912
    float* biasT  = att + QKVE;                       // 393,216 fp32
    float* tbl6   = biasT + (size_t)6 * 256 * 256;    // 9,450 fp32
    short* w1pack = (short*)(tbl6 + 9472);
    short* w2pack = w1pack + (size_t)768 * 192;
    short* wqpack = w2pack + (size_t)192 * 768;
    short* wppack = wqpack + (size_t)576 * 192;
    short* qbf    = wppack + (size_t)192 * 192;       // bf16, 12,582,912 each
    short* kbf    = qbf + QKVE;
    short* vtb    = kbf + QKVE;
    short* xmb    = vtb + QKVE;                       // bf16 x_mid, raster order

    hipLaunchKernelGGL(pack_w_k, dim3(288), dim3(64), 0, stream, fc1_w, w1pack, 192);
    hipLaunchKernelGGL(pack_w_k, dim3(288), dim3(64), 0, stream, fc2_w, w2pack, 768);
    hipLaunchKernelGGL(pack_w_k, dim3(216), dim3(64), 0, stream, qkv_w, wqpack, 192);
    hipLaunchKernelGGL(pack_w_k, dim3(72), dim3(64), 0, stream, proj_w, wppack, 192);
    hipLaunchKernelGGL(cpb_table_k, dim3(1575), dim3(64), 0, stream, cpb_w1, cpb_b1, cpb_w2, tbl6);
    hipLaunchKernelGGL(bias_k, dim3(1536), dim3(256), 0, stream, tbl6, biasT);
    hipLaunchKernelGGL(qkv_mfma_k, dim3(2048), dim3(256), 0, stream, x, wqpack, qkv_b, qbf, kbf, vtb);
    hipLaunchKernelGGL(attn_mfma_k, dim3(1536), dim3(256), 0, stream, qbf, kbf, vtb, biasT, logit_scale, att);
    hipLaunchKernelGGL(proj_mfma_k, dim3(2048), dim3(256), 0, stream, att, wppack, proj_b, x, norm1_g, norm1_b, out, xmb);
    hipLaunchKernelGGL(mlp_mfma_k, dim3(2048), dim3(512), 0, stream, xmb, w1pack, w2pack,
                       fc1_b, fc2_b, norm2_g, norm2_b, out);
}

// Round 7
// 419.251 us; speedup vs baseline: 7.0721x; 1.0084x over previous
//
#include <hip/hip_runtime.h>
#include <math.h>

// Problem constants
// B=2, T=8, H=64, W=64, C=192, WIN=(4,8,8), SHIFT=(2,4,4), HEADS=6, d=32
// N=256 tokens/window, nW=128 windows/batch, B_=256 windows total, HID=768

typedef short short8 __attribute__((ext_vector_type(8)));
typedef short short4v __attribute__((ext_vector_type(4)));
typedef float f32x4 __attribute__((ext_vector_type(4)));

__device__ __forceinline__ short f2bf(float f) {
    union { float f; unsigned u; } v; v.f = f;
    unsigned r = v.u + 0x7FFF + ((v.u >> 16) & 1);  // RNE
    return (short)(r >> 16);
}

// tanh-form GELU reduced to sigmoid: x * sigmoid(1.5957691*x*(1+0.044715*x^2))
__device__ __forceinline__ float gelu_fast(float x) {
    float s = x * x;
    float t = fmaf(0.044715f, s, 1.0f);
    float y = -1.5957691216057308f * x * t;
    return x / (1.0f + __expf(y));
}

// ---------------------------------------------------------------- K0: pack fp32 weight (Nout, K) -> bf16 fragment order
// frag (nt, kt): lane l holds W[nt*16+(l&15)][kt*32+(l>>4)*8+j]
// Works as B-frag (W^T as B) AND as A-frag (W as A) — layouts are identical.
__global__ __launch_bounds__(64) void pack_w_k(const float* __restrict__ w,
                                               short* __restrict__ dst, int K) {
    int lane = threadIdx.x;
    int ktn = K >> 5;
    int nt = blockIdx.x / ktn, kt = blockIdx.x % ktn;
    int r = lane & 15, q = lane >> 4;
    const float* src = w + (size_t)(nt * 16 + r) * K + kt * 32 + q * 8;
    short8 v;
#pragma unroll
    for (int j = 0; j < 8; j++) v[j] = f2bf(src[j]);
    ((short8*)dst)[(size_t)blockIdx.x * 64 + lane] = v;
}

// ---------------------------------------------------------------- K1a: CPB MLP table — one wave per m, shuffle reduction
__global__ __launch_bounds__(64) void cpb_table_k(const float* __restrict__ w1,
                                                  const float* __restrict__ b1,
                                                  const float* __restrict__ w2,
                                                  float* __restrict__ tbl6) {
    int m = blockIdx.x;
    int lane = threadIdx.x;
    int it = m / 225;
    int ih = (m / 15) % 15;
    int iw = m % 15;
    float r0 = (float)(it - 3) * (8.0f / 3.0f);
    float r1 = (float)(ih - 7) * (8.0f / 7.0f);
    float r2 = (float)(iw - 7) * (8.0f / 7.0f);
    float c0 = (r0 < 0.f ? -1.f : 1.f) * log2f(fabsf(r0) + 1.0f) * (1.0f / 3.0f);
    float c1 = (r1 < 0.f ? -1.f : 1.f) * log2f(fabsf(r1) + 1.0f) * (1.0f / 3.0f);
    float c2 = (r2 < 0.f ? -1.f : 1.f) * log2f(fabsf(r2) + 1.0f) * (1.0f / 3.0f);
    float hv[8];
#pragma unroll
    for (int j = 0; j < 8; j++) {
        int t = lane * 8 + j;
        hv[j] = fmaxf(0.0f, c0 * w1[3 * t] + c1 * w1[3 * t + 1] + c2 * w1[3 * t + 2] + b1[t]);
    }
#pragma unroll
    for (int head = 0; head < 6; head++) {
        float s = 0.f;
#pragma unroll
        for (int j = 0; j < 8; j++) s += hv[j] * w2[head * 512 + lane * 8 + j];
        s += __shfl_xor(s, 1);
        s += __shfl_xor(s, 2);
        s += __shfl_xor(s, 4);
        s += __shfl_xor(s, 8);
        s += __shfl_xor(s, 16);
        s += __shfl_xor(s, 32);
        if (lane == 0) tbl6[m * 6 + head] = s;
    }
}

// ---------------------------------------------------------------- K1b: biasT[h][key][query] = 16*sigmoid(cpb(query,key))  (TRANSPOSED)
__global__ __launch_bounds__(256) void bias_k(const float* __restrict__ tbl6,
                                              float* __restrict__ biasT) {
    int idx = blockIdx.x * 256 + threadIdx.x;  // h*65536 + key*256 + query
    int h = idx >> 16;
    int rem = idx & 65535;
    int jj = rem >> 8, ii = rem & 255;  // jj = key, ii = query
    int dt = (ii >> 6) - (jj >> 6) + 3;
    int dh = ((ii >> 3) & 7) - ((jj >> 3) & 7) + 7;
    int dw = (ii & 7) - (jj & 7) + 7;
    int rel = dt * 225 + dh * 15 + dw;
    float v = tbl6[rel * 6 + h];
    biasT[idx] = 16.0f / (1.0f + expf(-v));
}

// ---------------------------------------------------------------- K2: QKV via bf16 MFMA + shifted-window gather + q/k normalize
#define ZSTR 388
__global__ __launch_bounds__(256) void qkv_mfma_k(const float* __restrict__ x,
                                                  const short* __restrict__ wqp,
                                                  const float* __restrict__ qkv_b,
                                                  short* __restrict__ qbf,
                                                  short* __restrict__ kbf,
                                                  short* __restrict__ vtb) {
    __shared__ float Z[32 * ZSTR];  // q,k channels 0..383 (49664 B)
    int tid = threadIdx.x, lane = tid & 63, w = tid >> 6;
    int r = lane & 15, q = lane >> 4;
    int b_ = blockIdx.x >> 3, n0 = (blockIdx.x & 7) << 5;
    int b = b_ >> 7, win = b_ & 127;
    int wt = win >> 6, wh = (win >> 3) & 7, ww = win & 7;

    short8 af[2][6];
#pragma unroll
    for (int m = 0; m < 2; m++) {
        int n = n0 + m * 16 + r;
        int t0 = ((wt * 4 + (n >> 6)) + 2) & 7;
        int h0 = ((wh * 8 + ((n >> 3) & 7)) + 4) & 63;
        int w0 = ((ww * 8 + (n & 7)) + 4) & 63;
        const float* src = x + ((size_t)((b * 8 + t0) * 64 + h0) * 64 + w0) * 192 + q * 8;
#pragma unroll
        for (int kt = 0; kt < 6; kt++) {
            float4 x0 = *(const float4*)(src + kt * 32);
            float4 x1 = *(const float4*)(src + kt * 32 + 4);
            short8 v;
            v[0] = f2bf(x0.x); v[1] = f2bf(x0.y); v[2] = f2bf(x0.z); v[3] = f2bf(x0.w);
            v[4] = f2bf(x1.x); v[5] = f2bf(x1.y); v[6] = f2bf(x1.z); v[7] = f2bf(x1.w);
            af[m][kt] = v;
        }
    }

    for (int ntl = 0; ntl < 9; ntl++) {
        int nt = w * 9 + ntl;
        float bias = qkv_b[nt * 16 + r];
        short8 bfr[6];
#pragma unroll
        for (int kt = 0; kt < 6; kt++)
            bfr[kt] = ((const short8*)wqp)[(size_t)(nt * 6 + kt) * 64 + lane];
        f32x4 a0 = {bias, bias, bias, bias};
        f32x4 a1 = {bias, bias, bias, bias};
#pragma unroll
        for (int kt = 0; kt < 6; kt++) {
            a0 = __builtin_amdgcn_mfma_f32_16x16x32_bf16(af[0][kt], bfr[kt], a0, 0, 0, 0);
            a1 = __builtin_amdgcn_mfma_f32_16x16x32_bf16(af[1][kt], bfr[kt], a1, 0, 0, 0);
        }
        int col = nt * 16 + r;
        if (nt < 24) {  // q,k -> LDS for normalization
#pragma unroll
            for (int reg = 0; reg < 4; reg++) {
                Z[(q * 4 + reg) * ZSTR + col] = a0[reg];
                Z[(16 + q * 4 + reg) * ZSTR + col] = a1[reg];
            }
        } else {  // v -> global transposed bf16: vtb[(b_*6+h)*32+d][key]
            int ch = col - 384;
            int hh = ch >> 5, dd = ch & 31;
            short* vb = vtb + ((size_t)(b_ * 6 + hh) * 32 + dd) * 256 + n0;
            short4v p0, p1;
#pragma unroll
            for (int reg = 0; reg < 4; reg++) { p0[reg] = f2bf(a0[reg]); p1[reg] = f2bf(a1[reg]); }
            *(short4v*)(vb + q * 4) = p0;
            *(short4v*)(vb + 16 + q * 4) = p1;
        }
    }
    __syncthreads();
    for (int rw = tid; rw < 384; rw += 256) {
        int token = rw / 12, rr = rw - token * 12;
        int isq = rr < 6 ? 1 : 0;
        int h = isq ? rr : rr - 6;
        const float* rp = &Z[token * ZSTR + rr * 32];
        float ss = 0.f;
#pragma unroll
        for (int d = 0; d < 32; d++) ss += rp[d] * rp[d];
        float inv = 1.0f / fmaxf(sqrtf(ss), 1e-12f);
        short* dst = (isq ? qbf : kbf) + ((size_t)(b_ * 6 + h) * 256 + n0 + token) * 32;
#pragma unroll
        for (int d8 = 0; d8 < 4; d8++) {
            short8 v;
#pragma unroll
            for (int j = 0; j < 8; j++) v[j] = f2bf(rp[d8 * 8 + j] * inv);
            *(short8*)(dst + d8 * 8) = v;
        }
    }
}

// ---------------------------------------------------------------- K3: flash attention via bf16 MFMA, one block per (window, head)
#define KSTR 40
#define VSTR 264
#define PSTR 40
__global__ __launch_bounds__(256) void attn_mfma_k(const short* __restrict__ qbf,
                                                   const short* __restrict__ kbf,
                                                   const short* __restrict__ vtb,
                                                   const float* __restrict__ biasT,
                                                   const float* __restrict__ logit_scale,
                                                   float* __restrict__ att) {
    __shared__ short Ks[256 * KSTR];      // 20480 B
    __shared__ short Vs[32 * VSTR];       // 16896 B
    __shared__ short Ps[4][16 * PSTR];    // 5120 B (wave-private P tiles)
    int tid = threadIdx.x, lane = tid & 63, w = tid >> 6;
    int r = lane & 15, q = lane >> 4;
    int b_ = blockIdx.x / 6, h = blockIdx.x % 6;
    size_t base = (size_t)(b_ * 6 + h) * 8192;

    const short8* kg = (const short8*)(kbf + base);
    const short8* vg = (const short8*)(vtb + base);
    for (int i = tid; i < 1024; i += 256) {
        short8 kv = kg[i];
        *(short8*)&Ks[(i >> 2) * KSTR + (i & 3) * 8] = kv;
        short8 vv = vg[i];
        *(short8*)&Vs[(i >> 5) * VSTR + (i & 31) * 8] = vv;
    }

    short8 qf[4];
#pragma unroll
    for (int mt = 0; mt < 4; mt++)
        qf[mt] = *(const short8*)(qbf + base + (size_t)(w * 64 + mt * 16 + r) * 32 + q * 8);

    float scale = __expf(fminf(logit_scale[h], 4.6051702f));
    float M = scale + 16.0f;
    int win = b_ & 127;
    int wt4 = (win >> 6) * 4, wh8 = ((win >> 3) & 7) * 8, ww8 = (win & 7) * 8;
    auto region = [&](int n) {
        int ts = wt4 + (n >> 6), hs = wh8 + ((n >> 3) & 7), wsv = ww8 + (n & 7);
        int rt = ts < 4 ? 0 : (ts < 6 ? 1 : 2);
        int rh = hs < 56 ? 0 : (hs < 60 ? 1 : 2);
        int rw = wsv < 56 ? 0 : (wsv < 60 ? 1 : 2);
        return rt * 9 + rh * 3 + rw;
    };
    int rowreg[4][4];
#pragma unroll
    for (int mt = 0; mt < 4; mt++)
#pragma unroll
        for (int reg = 0; reg < 4; reg++)
            rowreg[mt][reg] = region(w * 64 + mt * 16 + q * 4 + reg);

    f32x4 O[4][2];
    float lp[4][4];
#pragma unroll
    for (int mt = 0; mt < 4; mt++) {
        O[mt][0] = (f32x4){0.f, 0.f, 0.f, 0.f};
        O[mt][1] = (f32x4){0.f, 0.f, 0.f, 0.f};
#pragma unroll
        for (int reg = 0; reg < 4; reg++) lp[mt][reg] = 0.f;
    }
    __syncthreads();

    const float* bh = biasT + ((size_t)h << 16);
    for (int s = 0; s < 8; s++) {
        short8 kf0 = *(const short8*)&Ks[(s * 32 + r) * KSTR + q * 8];
        short8 kf1 = *(const short8*)&Ks[(s * 32 + 16 + r) * KSTR + q * 8];
        short8 vf0 = *(const short8*)&Vs[r * VSTR + s * 32 + q * 8];
        short8 vf1 = *(const short8*)&Vs[(16 + r) * VSTR + s * 32 + q * 8];
        int cr0 = region(s * 32 + r);
        int cr1 = region(s * 32 + 16 + r);
#pragma unroll
        for (int mt = 0; mt < 4; mt++) {
            f32x4 s0 = {0.f, 0.f, 0.f, 0.f};
            f32x4 s1 = {0.f, 0.f, 0.f, 0.f};
            s0 = __builtin_amdgcn_mfma_f32_16x16x32_bf16(qf[mt], kf0, s0, 0, 0, 0);
            s1 = __builtin_amdgcn_mfma_f32_16x16x32_bf16(qf[mt], kf1, s1, 0, 0, 0);
            int qcol = w * 64 + mt * 16 + q * 4;
            float4 b0 = *(const float4*)(bh + (size_t)(s * 32 + r) * 256 + qcol);
            float4 b1 = *(const float4*)(bh + (size_t)(s * 32 + 16 + r) * 256 + qcol);
#pragma unroll
            for (int reg = 0; reg < 4; reg++) {
                float bb0 = (reg == 0 ? b0.x : reg == 1 ? b0.y : reg == 2 ? b0.z : b0.w);
                float bb1 = (reg == 0 ? b1.x : reg == 1 ? b1.y : reg == 2 ? b1.z : b1.w);
                float v0 = s0[reg] * scale + bb0 + (cr0 == rowreg[mt][reg] ? 0.f : -100.f) - M;
                float v1 = s1[reg] * scale + bb1 + (cr1 == rowreg[mt][reg] ? 0.f : -100.f) - M;
                float p0 = __expf(v0);
                float p1 = __expf(v1);
                lp[mt][reg] += p0 + p1;
                Ps[w][(q * 4 + reg) * PSTR + r] = f2bf(p0);
                Ps[w][(q * 4 + reg) * PSTR + 16 + r] = f2bf(p1);
            }
            short8 pa = *(const short8*)&Ps[w][r * PSTR + q * 8];
            O[mt][0] = __builtin_amdgcn_mfma_f32_16x16x32_bf16(pa, vf0, O[mt][0], 0, 0, 0);
            O[mt][1] = __builtin_amdgcn_mfma_f32_16x16x32_bf16(pa, vf1, O[mt][1], 0, 0, 0);
        }
    }

#pragma unroll
    for (int mt = 0; mt < 4; mt++)
#pragma unroll
        for (int reg = 0; reg < 4; reg++) {
            float v = lp[mt][reg];
            v += __shfl_xor(v, 1);
            v += __shfl_xor(v, 2);
            v += __shfl_xor(v, 4);
            v += __shfl_xor(v, 8);
            lp[mt][reg] = 1.0f / v;
        }
#pragma unroll
    for (int mt = 0; mt < 4; mt++)
#pragma unroll
        for (int nt = 0; nt < 2; nt++)
#pragma unroll
            for (int reg = 0; reg < 4; reg++) {
                int query = w * 64 + mt * 16 + q * 4 + reg;
                att[((size_t)b_ * 256 + query) * 192 + h * 32 + nt * 16 + r] =
                    O[mt][nt][reg] * lp[mt][reg];
            }
}

// ---------------------------------------------------------------- K4: out-proj via bf16 MFMA (swapped operands) + LN + roll-scatter + residual
// Also emits xmb: bf16 copy of x_mid in raster order for the MLP kernel.
__global__ __launch_bounds__(256) void proj_mfma_k(const float* __restrict__ att,
                                                   const short* __restrict__ wpp,
                                                   const float* __restrict__ proj_b,
                                                   const float* __restrict__ x,
                                                   const float* __restrict__ g1,
                                                   const float* __restrict__ b1n,
                                                   float* __restrict__ out,
                                                   short* __restrict__ xmb) {
    __shared__ float Z[32 * 196];
    __shared__ float ps[32][8];
    __shared__ float pss[32][8];
    __shared__ float mean_s[32], inv_s[32];
    int tid = threadIdx.x, lane = tid & 63, w = tid >> 6;
    int r = lane & 15, q = lane >> 4;
    int b_ = blockIdx.x >> 3, n0 = (blockIdx.x & 7) << 5;

    short8 af[2][6];
#pragma unroll
    for (int m = 0; m < 2; m++) {
        const float* src = att + ((size_t)b_ * 256 + n0 + m * 16 + r) * 192 + q * 8;
#pragma unroll
        for (int kt = 0; kt < 6; kt++) {
            float4 x0 = *(const float4*)(src + kt * 32);
            float4 x1 = *(const float4*)(src + kt * 32 + 4);
            short8 v;
            v[0] = f2bf(x0.x); v[1] = f2bf(x0.y); v[2] = f2bf(x0.z); v[3] = f2bf(x0.w);
            v[4] = f2bf(x1.x); v[5] = f2bf(x1.y); v[6] = f2bf(x1.z); v[7] = f2bf(x1.w);
            af[m][kt] = v;
        }
    }
    for (int ntl = 0; ntl < 3; ntl++) {
        int nt = w * 3 + ntl;
        f32x4 binit = *(const f32x4*)(proj_b + nt * 16 + q * 4);
        short8 bfr[6];
#pragma unroll
        for (int kt = 0; kt < 6; kt++)
            bfr[kt] = ((const short8*)wpp)[(size_t)(nt * 6 + kt) * 64 + lane];
        f32x4 a0 = binit, a1 = binit;
#pragma unroll
        for (int kt = 0; kt < 6; kt++) {
            // swapped: A = weight frag, B = token frag -> C/D col = token, rows = channels
            a0 = __builtin_amdgcn_mfma_f32_16x16x32_bf16(bfr[kt], af[0][kt], a0, 0, 0, 0);
            a1 = __builtin_amdgcn_mfma_f32_16x16x32_bf16(bfr[kt], af[1][kt], a1, 0, 0, 0);
        }
        *(f32x4*)&Z[(r) * 196 + nt * 16 + q * 4] = a0;
        *(f32x4*)&Z[(16 + r) * 196 + nt * 16 + q * 4] = a1;
    }
    __syncthreads();
    {
        int token = tid >> 3, part = tid & 7;
        float s = 0.f, ss = 0.f;
        const float* zr = &Z[token * 196 + part * 24];
#pragma unroll
        for (int c = 0; c < 24; c++) { float v = zr[c]; s += v; ss += v * v; }
        ps[token][part] = s; pss[token][part] = ss;
    }
    __syncthreads();
    if (tid < 32) {
        float s = 0.f, ss = 0.f;
#pragma unroll
        for (int p = 0; p < 8; p++) { s += ps[tid][p]; ss += pss[tid][p]; }
        float mean = s * (1.0f / 192.0f);
        float var = ss * (1.0f / 192.0f) - mean * mean;
        mean_s[tid] = mean;
        inv_s[tid] = 1.0f / sqrtf(var + 1e-5f);
    }
    __syncthreads();
    int b = b_ >> 7, win = b_ & 127;
    int wt = win >> 6, wh = (win >> 3) & 7, ww = win & 7;
    for (int idx = tid; idx < 6144; idx += 256) {
        int token = idx / 192;
        int ch = idx - token * 192;
        int n = n0 + token;
        int t0 = ((wt * 4 + (n >> 6)) + 2) & 7;
        int h0 = ((wh * 8 + ((n >> 3) & 7)) + 4) & 63;
        int w0 = ((ww * 8 + (n & 7)) + 4) & 63;
        size_t gb = ((size_t)((b * 8 + t0) * 64 + h0) * 64 + w0) * 192;
        float v = (Z[token * 196 + ch] - mean_s[token]) * inv_s[token] * g1[ch] + b1n[ch];
        float o = x[gb + ch] + v;
        out[gb + ch] = o;
        xmb[gb + ch] = f2bf(o);
    }
}

// ---------------------------------------------------------------- K5: MLP via bf16 MFMA, 64 tokens/block, chunked H, Z in registers
// 512 threads (8 waves), grid 1024. hid processed in 3 chunks of 256.
// Phase 1 (per chunk): wave w computes hid-tiles {c*16+2w, c*16+2w+1} x 4 token-tiles
//   (w1 frag reused across 4 m) -> H chunk LDS bf16.
// Phase 2 (per chunk): wave w owns Z patch (2 m-tiles x 3 nt) in registers;
//   per kk: 2 LDS H-frags + 3 w2 frags -> 6 MFMAs. w2 read 2x/block, w1 1x.
#define XSTR 200   // shorts: 64 x 192 X tile, pad 8
#define H2STR 264  // shorts: 64 x 256 H chunk, pad 8
#define ZFSTR 196  // floats: 64 x 192 Z, pad 4
__global__ __launch_bounds__(512, 4) void mlp_mfma_k(const short* __restrict__ xmb,
                                                     const short* __restrict__ w1p,
                                                     const short* __restrict__ w2p,
                                                     const float* __restrict__ fc1_b,
                                                     const float* __restrict__ fc2_b,
                                                     const float* __restrict__ g2,
                                                     const float* __restrict__ b2,
                                                     float* __restrict__ out) {
    __shared__ short Buf[64 * XSTR + 64 * H2STR];  // 59392 B; Z fp32 [64][196] (50176 B) overlays
    short* Xs = Buf;
    short* Hs = Buf + 64 * XSTR;
    float* Z = (float*)Buf;
    __shared__ float mean_s[64], inv_s[64];
    int tid = threadIdx.x;
    int lane = tid & 63, w = tid >> 6;   // w in 0..7
    int r = lane & 15, q = lane >> 4;
    size_t tok0 = (size_t)blockIdx.x * 64;

    // stage X tile (64 tokens x 192 ch, bf16) into LDS
    for (int i = tid; i < 1536; i += 512) {
        int token = i / 24, ch8 = (i - token * 24) * 8;
        short8 v = *(const short8*)(xmb + (tok0 + token) * 192 + ch8);
        *(short8*)&Xs[token * XSTR + ch8] = v;
    }
    __syncthreads();

    int mg = w >> 2;   // 0..1: owns m-tiles {2mg, 2mg+1} in phase 2
    int ng = w & 3;    // 0..3: owns out n-tiles {3ng, 3ng+1, 3ng+2} in phase 2
    f32x4 acc2[6];     // Z patch: [n(3)][mhalf(2)]
#pragma unroll
    for (int i = 0; i < 6; i++) acc2[i] = (f32x4){0.f, 0.f, 0.f, 0.f};

    for (int c = 0; c < 3; c++) {
        // ---- phase 1: hid tiles ntg = c*16 + 2w + {0,1}, all 4 token-tiles
        {
            int ntg0 = c * 16 + 2 * w;
            f32x4 a[2][4];
#pragma unroll
            for (int ntl = 0; ntl < 2; ntl++) {
                f32x4 binit = *(const f32x4*)(fc1_b + (ntg0 + ntl) * 16 + q * 4);
#pragma unroll
                for (int m = 0; m < 4; m++) a[ntl][m] = binit;
            }
#pragma unroll
            for (int kt = 0; kt < 6; kt++) {
                short8 w0 = ((const short8*)w1p)[(size_t)((ntg0) * 6 + kt) * 64 + lane];
                short8 w1f = ((const short8*)w1p)[(size_t)((ntg0 + 1) * 6 + kt) * 64 + lane];
                short8 xb[4];
#pragma unroll
                for (int m = 0; m < 4; m++)
                    xb[m] = *(const short8*)&Xs[(m * 16 + r) * XSTR + kt * 32 + q * 8];
#pragma unroll
                for (int m = 0; m < 4; m++) {
                    a[0][m] = __builtin_amdgcn_mfma_f32_16x16x32_bf16(w0, xb[m], a[0][m], 0, 0, 0);
                    a[1][m] = __builtin_amdgcn_mfma_f32_16x16x32_bf16(w1f, xb[m], a[1][m], 0, 0, 0);
                }
            }
            // GELU + store H chunk (lane holds 4 consecutive hid for one token)
#pragma unroll
            for (int ntl = 0; ntl < 2; ntl++) {
                int hcol = (2 * w + ntl) * 16 + q * 4;
#pragma unroll
                for (int m = 0; m < 4; m++) {
                    short4v p;
#pragma unroll
                    for (int reg = 0; reg < 4; reg++) p[reg] = f2bf(gelu_fast(a[ntl][m][reg]));
                    *(short4v*)&Hs[(m * 16 + r) * H2STR + hcol] = p;
                }
            }
        }
        __syncthreads();

        // ---- phase 2: accumulate Z from this H chunk (kk_global = c*8 + kk)
#pragma unroll
        for (int kk = 0; kk < 8; kk++) {
            short8 hb0 = *(const short8*)&Hs[((mg * 2) * 16 + r) * H2STR + kk * 32 + q * 8];
            short8 hb1 = *(const short8*)&Hs[((mg * 2 + 1) * 16 + r) * H2STR + kk * 32 + q * 8];
            int kkg = c * 8 + kk;
#pragma unroll
            for (int n = 0; n < 3; n++) {
                int ntz = ng * 3 + n;
                short8 wf = ((const short8*)w2p)[(size_t)(ntz * 24 + kkg) * 64 + lane];
                acc2[n * 2 + 0] = __builtin_amdgcn_mfma_f32_16x16x32_bf16(wf, hb0, acc2[n * 2 + 0], 0, 0, 0);
                acc2[n * 2 + 1] = __builtin_amdgcn_mfma_f32_16x16x32_bf16(wf, hb1, acc2[n * 2 + 1], 0, 0, 0);
            }
        }
        __syncthreads();  // H chunk consumed; next phase-1 may overwrite
    }

    // ---- write Z (+fc2 bias) to LDS (overlays Xs/Hs — safe after last barrier)
#pragma unroll
    for (int n = 0; n < 3; n++) {
        int ntz = ng * 3 + n;
        f32x4 b4 = *(const f32x4*)(fc2_b + ntz * 16 + q * 4);
#pragma unroll
        for (int mh = 0; mh < 2; mh++) {
            int token = (mg * 2 + mh) * 16 + r;
            f32x4 zv = acc2[n * 2 + mh] + b4;
            *(f32x4*)&Z[token * ZFSTR + ntz * 16 + q * 4] = zv;
        }
    }
    __syncthreads();

    // ---- LN stats: 8 lanes per token (in-wave butterfly over part bits 0..2)
    {
        int token = w * 8 + (lane >> 3), part = lane & 7;
        float s = 0.f, ss = 0.f;
        const float* zr = &Z[token * ZFSTR + part * 24];
#pragma unroll
        for (int ccc = 0; ccc < 24; ccc++) { float v = zr[ccc]; s += v; ss += v * v; }
        s += __shfl_xor(s, 1); ss += __shfl_xor(ss, 1);
        s += __shfl_xor(s, 2); ss += __shfl_xor(ss, 2);
        s += __shfl_xor(s, 4); ss += __shfl_xor(ss, 4);
        if (part == 0) {
            float mean = s * (1.0f / 192.0f);
            float var = ss * (1.0f / 192.0f) - mean * mean;
            mean_s[token] = mean;
            inv_s[token] = 1.0f / sqrtf(var + 1e-5f);
        }
    }
    __syncthreads();
    // ---- epilogue: out = x_mid + LN(Z)*g2 + b2   (12288 elems, 24/thread)
    for (int rep = 0; rep < 24; rep++) {
        int idx = rep * 512 + tid;
        int token = idx / 192;
        int ch = idx - token * 192;
        float v = (Z[token * ZFSTR + ch] - mean_s[token]) * inv_s[token] * g2[ch] + b2[ch];
        size_t gi = (tok0 + token) * 192 + ch;
        out[gi] = out[gi] + v;
    }
}

// ---------------------------------------------------------------- launch
extern "C" void kernel_launch(void* const* d_in, const int* in_sizes, int n_in,
                              void* d_out, int out_size, void* d_ws, size_t ws_size,
                              hipStream_t stream) {
    const float* x           = (const float*)d_in[0];
    const float* qkv_w       = (const float*)d_in[1];
    const float* qkv_b       = (const float*)d_in[2];
    const float* proj_w      = (const float*)d_in[3];
    const float* proj_b      = (const float*)d_in[4];
    const float* cpb_w1      = (const float*)d_in[5];
    const float* cpb_b1      = (const float*)d_in[6];
    const float* cpb_w2      = (const float*)d_in[7];
    const float* logit_scale = (const float*)d_in[8];
    const float* norm1_g     = (const float*)d_in[9];
    const float* norm1_b     = (const float*)d_in[10];
    const float* norm2_g     = (const float*)d_in[11];
    const float* norm2_b     = (const float*)d_in[12];
    const float* fc1_w       = (const float*)d_in[13];
    const float* fc1_b       = (const float*)d_in[14];
    const float* fc2_w       = (const float*)d_in[15];
    const float* fc2_b       = (const float*)d_in[16];
    float* out = (float*)d_out;

    float* ws = (float*)d_ws;
    const size_t QKVE = (size_t)256 * 6 * 256 * 32;   // 12,582,912 elems
    float* att    = ws;                               // fp32, 12,582,912
    float* biasT  = att + QKVE;                       // 393,216 fp32
    float* tbl6   = biasT + (size_t)6 * 256 * 256;    // 9,450 fp32
    short* w1pack = (short*)(tbl6 + 9472);
    short* w2pack = w1pack + (size_t)768 * 192;
    short* wqpack = w2pack + (size_t)192 * 768;
    short* wppack = wqpack + (size_t)576 * 192;
    short* qbf    = wppack + (size_t)192 * 192;       // bf16, 12,582,912 each
    short* kbf    = qbf + QKVE;
    short* vtb    = kbf + QKVE;
    short* xmb    = vtb + QKVE;                       // bf16 x_mid, raster order

    hipLaunchKernelGGL(pack_w_k, dim3(288), dim3(64), 0, stream, fc1_w, w1pack, 192);
    hipLaunchKernelGGL(pack_w_k, dim3(288), dim3(64), 0, stream, fc2_w, w2pack, 768);
    hipLaunchKernelGGL(pack_w_k, dim3(216), dim3(64), 0, stream, qkv_w, wqpack, 192);
    hipLaunchKernelGGL(pack_w_k, dim3(72), dim3(64), 0, stream, proj_w, wppack, 192);
    hipLaunchKernelGGL(cpb_table_k, dim3(1575), dim3(64), 0, stream, cpb_w1, cpb_b1, cpb_w2, tbl6);
    hipLaunchKernelGGL(bias_k, dim3(1536), dim3(256), 0, stream, tbl6, biasT);
    hipLaunchKernelGGL(qkv_mfma_k, dim3(2048), dim3(256), 0, stream, x, wqpack, qkv_b, qbf, kbf, vtb);
    hipLaunchKernelGGL(attn_mfma_k, dim3(1536), dim3(256), 0, stream, qbf, kbf, vtb, biasT, logit_scale, att);
    hipLaunchKernelGGL(proj_mfma_k, dim3(2048), dim3(256), 0, stream, att, wppack, proj_b, x, norm1_g, norm1_b, out, xmb);
    hipLaunchKernelGGL(mlp_mfma_k, dim3(1024), dim3(512), 0, stream, xmb, w1pack, w2pack,
                       fc1_b, fc2_b, norm2_g, norm2_b, out);
}